// Round 1
// baseline (4472.426 us; speedup 1.0000x reference)
//
#include <hip/hip_runtime.h>
#include <hip/hip_bf16.h>
#include <math.h>

#define S 2048
#define DM 2048
#define NH 16
#define DH 128
#define DR 64
#define DKV 512
#define DQ 1024
#define DQK 192  // DH + DR

// ---------------- RoPE cos/sin table ----------------
__global__ void rope_table_kernel(float* __restrict__ cosT, float* __restrict__ sinT) {
    int idx = blockIdx.x * blockDim.x + threadIdx.x;  // over S * (DR/2)
    if (idx >= S * (DR / 2)) return;
    int pos = idx / (DR / 2);
    int j   = idx % (DR / 2);
    // inv_freq = 10000^(-(2j)/DR)
    float inv = __expf(-((float)(2 * j) / (float)DR) * logf(10000.0f));
    float ang = (float)pos * inv;
    cosT[idx] = cosf(ang);
    sinT[idx] = sinf(ang);
}

// ---------------- fp32 tiled GEMM: C[M,N] = A[M,K] @ B[K,N], row-major ----------------
// M%64==0, N%64==0, K%16==0 (all shapes here satisfy this)
#define TM 64
#define TN 64
#define TK 16

__global__ __launch_bounds__(256) void gemm_f32_kernel(const float* __restrict__ A,
                                                       const float* __restrict__ B,
                                                       float* __restrict__ C,
                                                       int M, int N, int K) {
    __shared__ float As[TK][TM + 4];  // stride 68 floats = 272B (16B aligned, bank-shift 4)
    __shared__ float Bs[TK][TN + 4];
    const int tid = threadIdx.x;
    const int tx = tid & 15;
    const int ty = tid >> 4;
    const int bm = blockIdx.y * TM;
    const int bn = blockIdx.x * TN;

    float acc[4][4] = {};

    for (int k0 = 0; k0 < K; k0 += TK) {
        // load A tile 64x16 (float4 per thread)
        {
            int row = tid >> 2;
            int kk  = (tid & 3) * 4;
            float4 a = *reinterpret_cast<const float4*>(&A[(size_t)(bm + row) * K + k0 + kk]);
            As[kk + 0][row] = a.x;
            As[kk + 1][row] = a.y;
            As[kk + 2][row] = a.z;
            As[kk + 3][row] = a.w;
        }
        // load B tile 16x64 (float4 per thread)
        {
            int row = tid >> 4;
            int cc  = (tid & 15) * 4;
            float4 b = *reinterpret_cast<const float4*>(&B[(size_t)(k0 + row) * N + bn + cc]);
            *reinterpret_cast<float4*>(&Bs[row][cc]) = b;
        }
        __syncthreads();

#pragma unroll
        for (int kk = 0; kk < TK; ++kk) {
            float a[4], b[4];
#pragma unroll
            for (int i = 0; i < 4; ++i) a[i] = As[kk][ty * 4 + i];
#pragma unroll
            for (int j = 0; j < 4; ++j) b[j] = Bs[kk][tx * 4 + j];
#pragma unroll
            for (int i = 0; i < 4; ++i)
#pragma unroll
                for (int j = 0; j < 4; ++j) acc[i][j] = fmaf(a[i], b[j], acc[i][j]);
        }
        __syncthreads();
    }

#pragma unroll
    for (int i = 0; i < 4; ++i) {
        float4 v = make_float4(acc[i][0], acc[i][1], acc[i][2], acc[i][3]);
        *reinterpret_cast<float4*>(&C[(size_t)(bm + ty * 4 + i) * N + bn + tx * 4]) = v;
    }
}

// ---------------- assemble q/k: (h, s, 192) with RoPE on last 64 dims ----------------
__global__ void assemble_qk_kernel(const float* __restrict__ c_raw,  // (s, NH*DH)
                                   const float* __restrict__ r_raw,  // (s, NH*DR)
                                   const float* __restrict__ cosT,
                                   const float* __restrict__ sinT,
                                   float* __restrict__ outp,         // (NH, S, DQK)
                                   int total) {
    int idx = blockIdx.x * blockDim.x + threadIdx.x;
    if (idx >= total) return;
    int d    = idx % DQK;
    int rest = idx / DQK;
    int pos  = rest % S;
    int h    = rest / S;
    float val;
    if (d < DH) {
        val = c_raw[(size_t)pos * (NH * DH) + h * DH + d];
    } else {
        int r = d - DH;
        int j = r >> 1;
        float t1 = r_raw[(size_t)pos * (NH * DR) + h * DR + 2 * j];
        float t2 = r_raw[(size_t)pos * (NH * DR) + h * DR + 2 * j + 1];
        float c  = cosT[pos * (DR / 2) + j];
        float s  = sinT[pos * (DR / 2) + j];
        val = (r & 1) ? (t1 * s + t2 * c) : (t1 * c - t2 * s);
    }
    outp[idx] = val;
}

// ---------------- causal attention, online softmax, one block per (head, q-row) ----------------
__global__ __launch_bounds__(256) void attn_kernel(const float* __restrict__ q,      // (NH, S, DQK)
                                                   const float* __restrict__ k,      // (NH, S, DQK)
                                                   const float* __restrict__ v_raw,  // (s, NH*DH)
                                                   float* __restrict__ outp) {       // (s, NH*DH)
    const int h   = blockIdx.x;
    const int qi  = blockIdx.y;
    const int tid = threadIdx.x;
    const float scale = 1.0f / sqrtf((float)DQK);

    __shared__ float q_s[DQK];
    __shared__ float p_s[256];
    __shared__ float red[256];

    if (tid < DQK) q_s[tid] = q[((size_t)h * S + qi) * DQK + tid];
    __syncthreads();

    float m = -INFINITY, l = 0.0f, acc = 0.0f;
    const int nk = qi + 1;

    for (int t0 = 0; t0 < nk; t0 += 256) {
        int j = t0 + tid;
        float s = -INFINITY;
        if (j < nk) {
            const float* kr = k + ((size_t)h * S + j) * DQK;
            float dot = 0.0f;
#pragma unroll
            for (int d = 0; d < DQK; d += 4) {
                float4 kv = *reinterpret_cast<const float4*>(&kr[d]);
                dot += q_s[d] * kv.x + q_s[d + 1] * kv.y + q_s[d + 2] * kv.z + q_s[d + 3] * kv.w;
            }
            s = dot * scale;
        }
        // block max
        red[tid] = s;
        __syncthreads();
        for (int off = 128; off > 0; off >>= 1) {
            if (tid < off) red[tid] = fmaxf(red[tid], red[tid + off]);
            __syncthreads();
        }
        float m_new = fmaxf(m, red[0]);
        __syncthreads();  // protect red before reuse

        float p = (j < nk) ? __expf(s - m_new) : 0.0f;
        p_s[tid] = p;
        red[tid] = p;
        __syncthreads();
        for (int off = 128; off > 0; off >>= 1) {
            if (tid < off) red[tid] += red[tid + off];
            __syncthreads();
        }
        float tsum = red[0];

        float r = __expf(m - m_new);
        l = l * r + tsum;
        m = m_new;

        int cnt = min(256, nk - t0);
        if (tid < DH) {
            acc *= r;
            const float* vp = v_raw + (size_t)t0 * (NH * DH) + h * DH + tid;
            for (int jj = 0; jj < cnt; ++jj) acc = fmaf(p_s[jj], vp[(size_t)jj * (NH * DH)], acc);
        }
        __syncthreads();
    }

    if (tid < DH) outp[(size_t)qi * (NH * DH) + h * DH + tid] = acc / l;
}

// ---------------- launch ----------------
extern "C" void kernel_launch(void* const* d_in, const int* in_sizes, int n_in,
                              void* d_out, int out_size, void* d_ws, size_t ws_size,
                              hipStream_t stream) {
    const float* x         = (const float*)d_in[0];
    // d_in[1] = mask (causality computed directly)
    const float* W_kv_down = (const float*)d_in[2];
    const float* W_k_up    = (const float*)d_in[3];
    const float* W_v_up    = (const float*)d_in[4];
    const float* W_q_down  = (const float*)d_in[5];
    const float* W_q_up    = (const float*)d_in[6];
    const float* W_q_rope  = (const float*)d_in[7];
    const float* W_k_rope  = (const float*)d_in[8];
    const float* W_out     = (const float*)d_in[9];
    float* out = (float*)d_out;

    float* w = (float*)d_ws;
    size_t off = 0;
    float* cosT    = w + off; off += (size_t)S * (DR / 2);
    float* sinT    = w + off; off += (size_t)S * (DR / 2);
    float* down_kv = w + off; off += (size_t)S * DKV;
    float* down_q  = w + off; off += (size_t)S * DQ;
    float* kc_raw  = w + off; off += (size_t)S * NH * DH;
    float* v_raw   = w + off; off += (size_t)S * NH * DH;
    float* qc_raw  = w + off; off += (size_t)S * NH * DH;
    float* qr_raw  = w + off; off += (size_t)S * NH * DR;
    float* kr_raw  = w + off; off += (size_t)S * NH * DR;
    float* q_asm   = w + off; off += (size_t)NH * S * DQK;
    float* k_asm   = w + off; off += (size_t)NH * S * DQK;
    float* attn_out = qc_raw;  // reuse: qc_raw dead after q assembled

    rope_table_kernel<<<(S * (DR / 2) + 255) / 256, 256, 0, stream>>>(cosT, sinT);

    auto gemm = [&](const float* A, const float* B, float* C, int M, int N, int K) {
        dim3 grid(N / TN, M / TM);
        gemm_f32_kernel<<<grid, 256, 0, stream>>>(A, B, C, M, N, K);
    };

    gemm(x, W_kv_down, down_kv, S, DKV, DM);       // (2048,512)
    gemm(x, W_q_down, down_q, S, DQ, DM);          // (2048,1024)
    gemm(x, W_k_rope, kr_raw, S, NH * DR, DM);     // (2048,1024)
    gemm(down_kv, W_k_up, kc_raw, S, NH * DH, DKV);// (2048,2048)
    gemm(down_kv, W_v_up, v_raw, S, NH * DH, DKV); // (2048,2048)
    gemm(down_q, W_q_up, qc_raw, S, NH * DH, DQ);  // (2048,2048)
    gemm(down_q, W_q_rope, qr_raw, S, NH * DR, DQ);// (2048,1024)

    int total = NH * S * DQK;
    assemble_qk_kernel<<<(total + 255) / 256, 256, 0, stream>>>(qc_raw, qr_raw, cosT, sinT, q_asm, total);
    assemble_qk_kernel<<<(total + 255) / 256, 256, 0, stream>>>(kc_raw, kr_raw, cosT, sinT, k_asm, total);

    attn_kernel<<<dim3(NH, S), 256, 0, stream>>>(q_asm, k_asm, v_raw, attn_out);

    gemm(attn_out, W_out, out, S, DM, DM);         // final projection
}

// Round 2
// 1201.240 us; speedup vs baseline: 3.7232x; 3.7232x over previous
//
#include <hip/hip_runtime.h>
#include <hip/hip_bf16.h>
#include <math.h>

#define S 2048
#define DM 2048
#define NH 16
#define DH 128
#define DR 64
#define DKV 512
#define DQ 1024
#define DQK 192  // DH + DR

typedef __bf16 bf16x8 __attribute__((ext_vector_type(8)));
typedef float f32x4 __attribute__((ext_vector_type(4)));
typedef unsigned short u16;

__device__ inline unsigned int pack2_bf16(float a, float b) {
    __hip_bfloat16 ha = __float2bfloat16(a);
    __hip_bfloat16 hb = __float2bfloat16(b);
    unsigned short ua = *reinterpret_cast<unsigned short*>(&ha);
    unsigned short ub = *reinterpret_cast<unsigned short*>(&hb);
    return (unsigned int)ua | ((unsigned int)ub << 16);
}

// ---------------- RoPE cos/sin table ----------------
__global__ void rope_table_kernel(float* __restrict__ cosT, float* __restrict__ sinT) {
    int idx = blockIdx.x * blockDim.x + threadIdx.x;
    if (idx >= S * (DR / 2)) return;
    int pos = idx / (DR / 2);
    int j   = idx % (DR / 2);
    float inv = __expf(-((float)(2 * j) / (float)DR) * logf(10000.0f));
    float ang = (float)pos * inv;
    cosT[idx] = cosf(ang);
    sinT[idx] = sinf(ang);
}

// ---------------- fp32 tiled GEMM (unchanged) ----------------
#define TM 64
#define TN 64
#define TK 16

__global__ __launch_bounds__(256) void gemm_f32_kernel(const float* __restrict__ A,
                                                       const float* __restrict__ B,
                                                       float* __restrict__ C,
                                                       int M, int N, int K) {
    __shared__ float As[TK][TM + 4];
    __shared__ float Bs[TK][TN + 4];
    const int tid = threadIdx.x;
    const int tx = tid & 15;
    const int ty = tid >> 4;
    const int bm = blockIdx.y * TM;
    const int bn = blockIdx.x * TN;

    float acc[4][4] = {};

    for (int k0 = 0; k0 < K; k0 += TK) {
        {
            int row = tid >> 2;
            int kk  = (tid & 3) * 4;
            float4 a = *reinterpret_cast<const float4*>(&A[(size_t)(bm + row) * K + k0 + kk]);
            As[kk + 0][row] = a.x;
            As[kk + 1][row] = a.y;
            As[kk + 2][row] = a.z;
            As[kk + 3][row] = a.w;
        }
        {
            int row = tid >> 4;
            int cc  = (tid & 15) * 4;
            float4 b = *reinterpret_cast<const float4*>(&B[(size_t)(k0 + row) * N + bn + cc]);
            *reinterpret_cast<float4*>(&Bs[row][cc]) = b;
        }
        __syncthreads();

#pragma unroll
        for (int kk = 0; kk < TK; ++kk) {
            float a[4], b[4];
#pragma unroll
            for (int i = 0; i < 4; ++i) a[i] = As[kk][ty * 4 + i];
#pragma unroll
            for (int j = 0; j < 4; ++j) b[j] = Bs[kk][tx * 4 + j];
#pragma unroll
            for (int i = 0; i < 4; ++i)
#pragma unroll
                for (int j = 0; j < 4; ++j) acc[i][j] = fmaf(a[i], b[j], acc[i][j]);
        }
        __syncthreads();
    }

#pragma unroll
    for (int i = 0; i < 4; ++i) {
        float4 v = make_float4(acc[i][0], acc[i][1], acc[i][2], acc[i][3]);
        *reinterpret_cast<float4*>(&C[(size_t)(bm + ty * 4 + i) * N + bn + tx * 4]) = v;
    }
}

// ---------------- assemble q/k -> bf16 (NH, S, 192), RoPE on last 64, optional scale ----------------
__global__ void assemble_qk_bf16_kernel(const float* __restrict__ c_raw,  // (s, NH*DH)
                                        const float* __restrict__ r_raw,  // (s, NH*DR)
                                        const float* __restrict__ cosT,
                                        const float* __restrict__ sinT,
                                        u16* __restrict__ outp,           // (NH, S, DQK) bf16 bits
                                        float scale, int total) {
    int idx = blockIdx.x * blockDim.x + threadIdx.x;
    if (idx >= total) return;
    int d    = idx % DQK;
    int rest = idx / DQK;
    int pos  = rest % S;
    int h    = rest / S;
    float val;
    if (d < DH) {
        val = c_raw[(size_t)pos * (NH * DH) + h * DH + d];
    } else {
        int r = d - DH;
        int j = r >> 1;
        float t1 = r_raw[(size_t)pos * (NH * DR) + h * DR + 2 * j];
        float t2 = r_raw[(size_t)pos * (NH * DR) + h * DR + 2 * j + 1];
        float c  = cosT[pos * (DR / 2) + j];
        float s  = sinT[pos * (DR / 2) + j];
        val = (r & 1) ? (t1 * s + t2 * c) : (t1 * c - t2 * s);
    }
    __hip_bfloat16 hb = __float2bfloat16(val * scale);
    outp[idx] = *reinterpret_cast<u16*>(&hb);
}

// ---------------- V transpose: (s, NH*DH) f32 -> (NH, DH, S) bf16 ----------------
__global__ __launch_bounds__(256) void v_transpose_bf16_kernel(const float* __restrict__ v_raw,
                                                               u16* __restrict__ vt) {
    __shared__ u16 tile[64][65];
    const int j0 = blockIdx.x * 64;
    const int d0 = blockIdx.y * 64;
    const int h  = blockIdx.z;
    const int tx = threadIdx.x & 15;
    const int ty = threadIdx.x >> 4;
#pragma unroll
    for (int rep = 0; rep < 4; ++rep) {
        int j = rep * 16 + ty;
        float4 v = *reinterpret_cast<const float4*>(
            &v_raw[(size_t)(j0 + j) * (NH * DH) + h * DH + d0 + tx * 4]);
        __hip_bfloat16 b0 = __float2bfloat16(v.x);
        __hip_bfloat16 b1 = __float2bfloat16(v.y);
        __hip_bfloat16 b2 = __float2bfloat16(v.z);
        __hip_bfloat16 b3 = __float2bfloat16(v.w);
        tile[j][tx * 4 + 0] = *reinterpret_cast<u16*>(&b0);
        tile[j][tx * 4 + 1] = *reinterpret_cast<u16*>(&b1);
        tile[j][tx * 4 + 2] = *reinterpret_cast<u16*>(&b2);
        tile[j][tx * 4 + 3] = *reinterpret_cast<u16*>(&b3);
    }
    __syncthreads();
#pragma unroll
    for (int rep = 0; rep < 4; ++rep) {
        int d = rep * 16 + ty;
        uint2 w;
        w.x = (unsigned int)tile[tx * 4 + 0][d] | ((unsigned int)tile[tx * 4 + 1][d] << 16);
        w.y = (unsigned int)tile[tx * 4 + 2][d] | ((unsigned int)tile[tx * 4 + 3][d] << 16);
        *reinterpret_cast<uint2*>(&vt[((size_t)h * DH + d0 + d) * S + j0 + tx * 4]) = w;
    }
}

// ---------------- MFMA flash attention ----------------
// 1 wave per block; wave owns 16 q-rows of one head. KV tiles of 32.
// QK^T swapped (A=K, B=Q) -> S^T (col=q, row=key); PV swapped (A=V^T, B=P) -> O^T (col=q, row=dv).
__global__ __launch_bounds__(64) void attn_mfma_kernel(const u16* __restrict__ q,   // (NH,S,192) pre-scaled
                                                       const u16* __restrict__ k,   // (NH,S,192)
                                                       const u16* __restrict__ vt,  // (NH,DH,S)
                                                       float* __restrict__ outp) {  // (S, NH*DH)
    const int h    = blockIdx.y;
    const int q0   = ((int)gridDim.x - 1 - (int)blockIdx.x) * 16;  // big tiles dispatch first
    const int lane = threadIdx.x;
    const int col  = lane & 15;  // q_local for B/D; key_local / dv_local for A-loads
    const int g    = lane >> 4;  // 0..3

    __shared__ __align__(16) char p_lds[1024];  // P tile: [q][j] bf16, XOR-swizzled
    const int swz = (col & 3) << 4;

    // Q fragments (B-operand): lane holds Q[q0+col][g*8+e + 32c]
    bf16x8 qf[6];
    const u16* qbase = q + ((size_t)h * S + q0 + col) * DQK + g * 8;
#pragma unroll
    for (int c = 0; c < 6; ++c) qf[c] = *reinterpret_cast<const bf16x8*>(qbase + c * 32);

    f32x4 acc[8];
#pragma unroll
    for (int c = 0; c < 8; ++c) acc[c] = f32x4{0.f, 0.f, 0.f, 0.f};
    float m_run = -1e30f, l_run = 0.f;

    const int kend = q0 + 16;
    for (int j0 = 0; j0 < kend; j0 += 32) {
        const bool do_t1 = (j0 + 16) < kend;
        // ---- QK^T
        f32x4 st[2];
        st[0] = f32x4{0.f, 0.f, 0.f, 0.f};
        st[1] = f32x4{0.f, 0.f, 0.f, 0.f};
        const u16* kbase = k + ((size_t)h * S + j0 + col) * DQK + g * 8;
#pragma unroll
        for (int c = 0; c < 6; ++c) {
            bf16x8 kf = *reinterpret_cast<const bf16x8*>(kbase + c * 32);
            st[0] = __builtin_amdgcn_mfma_f32_16x16x32_bf16(kf, qf[c], st[0], 0, 0, 0);
        }
        if (do_t1) {
            const u16* kbase1 = kbase + (size_t)16 * DQK;
#pragma unroll
            for (int c = 0; c < 6; ++c) {
                bf16x8 kf = *reinterpret_cast<const bf16x8*>(kbase1 + c * 32);
                st[1] = __builtin_amdgcn_mfma_f32_16x16x32_bf16(kf, qf[c], st[1], 0, 0, 0);
            }
        } else {
            st[1] = f32x4{-1e30f, -1e30f, -1e30f, -1e30f};
        }
        // ---- causal mask: element key = j0+16t+4g+r, q = q0+col
#pragma unroll
        for (int t = 0; t < 2; ++t) {
            if (j0 + 16 * t + 15 > q0) {  // tile crosses diagonal (uniform)
#pragma unroll
                for (int r = 0; r < 4; ++r) {
                    int key = j0 + 16 * t + 4 * g + r;
                    st[t][r] = (key > q0 + col) ? -1e30f : st[t][r];
                }
            }
        }
        // ---- online softmax (stats per q = per lane)
        float tmax = fmaxf(fmaxf(fmaxf(st[0][0], st[0][1]), fmaxf(st[0][2], st[0][3])),
                           fmaxf(fmaxf(st[1][0], st[1][1]), fmaxf(st[1][2], st[1][3])));
        tmax = fmaxf(tmax, __shfl_xor(tmax, 16));
        tmax = fmaxf(tmax, __shfl_xor(tmax, 32));
        float m_new = fmaxf(m_run, tmax);
        float r_scale = __expf(m_run - m_new);
        float p[8];
        float psum = 0.f;
#pragma unroll
        for (int t = 0; t < 2; ++t)
#pragma unroll
            for (int r = 0; r < 4; ++r) {
                float pv = __expf(st[t][r] - m_new);
                p[t * 4 + r] = pv;
                psum += pv;
            }
        psum += __shfl_xor(psum, 16);
        psum += __shfl_xor(psum, 32);
        l_run = l_run * r_scale + psum;
        m_run = m_new;
#pragma unroll
        for (int c = 0; c < 8; ++c) {
            acc[c][0] *= r_scale; acc[c][1] *= r_scale;
            acc[c][2] *= r_scale; acc[c][3] *= r_scale;
        }
        // ---- P -> LDS [q][j] bf16 (lane holds q=col, j=16t+4g+r)
        __syncthreads();  // WAR: previous iteration's read done
#pragma unroll
        for (int t = 0; t < 2; ++t) {
            uint2 w;
            w.x = pack2_bf16(p[t * 4 + 0], p[t * 4 + 1]);
            w.y = pack2_bf16(p[t * 4 + 2], p[t * 4 + 3]);
            int jb = (t * 16 + 4 * g) * 2;
            *reinterpret_cast<uint2*>(&p_lds[col * 64 + (jb ^ swz)]) = w;
        }
        __syncthreads();  // RAW: P visible to all lanes
        // ---- PV: A = V^T rows (dv), B = P, K = 32 keys
        bf16x8 pf = *reinterpret_cast<const bf16x8*>(&p_lds[col * 64 + ((g * 16) ^ swz)]);
        const u16* vb = vt + ((size_t)h * DH + col) * S + j0 + g * 8;
#pragma unroll
        for (int c = 0; c < 8; ++c) {
            bf16x8 vf = *reinterpret_cast<const bf16x8*>(vb + (size_t)c * 16 * S);
            acc[c] = __builtin_amdgcn_mfma_f32_16x16x32_bf16(vf, pf, acc[c], 0, 0, 0);
        }
    }

    // ---- epilogue: O^T col=q(col), row=dv=16c+4g+r
    float inv_l = 1.0f / l_run;
#pragma unroll
    for (int c = 0; c < 8; ++c)
#pragma unroll
        for (int r = 0; r < 4; ++r)
            outp[(size_t)(q0 + col) * (NH * DH) + h * DH + 16 * c + 4 * g + r] = acc[c][r] * inv_l;
}

// ---------------- launch ----------------
extern "C" void kernel_launch(void* const* d_in, const int* in_sizes, int n_in,
                              void* d_out, int out_size, void* d_ws, size_t ws_size,
                              hipStream_t stream) {
    const float* x         = (const float*)d_in[0];
    const float* W_kv_down = (const float*)d_in[2];
    const float* W_k_up    = (const float*)d_in[3];
    const float* W_v_up    = (const float*)d_in[4];
    const float* W_q_down  = (const float*)d_in[5];
    const float* W_q_up    = (const float*)d_in[6];
    const float* W_q_rope  = (const float*)d_in[7];
    const float* W_k_rope  = (const float*)d_in[8];
    const float* W_out     = (const float*)d_in[9];
    float* out = (float*)d_out;

    float* w = (float*)d_ws;
    size_t off = 0;
    float* cosT    = w + off; off += (size_t)S * (DR / 2);
    float* sinT    = w + off; off += (size_t)S * (DR / 2);
    float* down_kv = w + off; off += (size_t)S * DKV;
    float* down_q  = w + off; off += (size_t)S * DQ;
    float* kc_raw  = w + off; off += (size_t)S * NH * DH;
    float* v_raw   = w + off; off += (size_t)S * NH * DH;
    float* qc_raw  = w + off; off += (size_t)S * NH * DH;
    float* qr_raw  = w + off; off += (size_t)S * NH * DR;
    float* kr_raw  = w + off; off += (size_t)S * NH * DR;
    u16* q_bf = (u16*)(w + off);
    u16* k_bf = q_bf + (size_t)NH * S * DQK;
    u16* vt   = k_bf + (size_t)NH * S * DQK;
    float* attn_out = qc_raw;  // reuse: qc_raw dead after q assembled

    rope_table_kernel<<<(S * (DR / 2) + 255) / 256, 256, 0, stream>>>(cosT, sinT);

    auto gemm = [&](const float* A, const float* B, float* C, int M, int N, int K) {
        dim3 grid(N / TN, M / TM);
        gemm_f32_kernel<<<grid, 256, 0, stream>>>(A, B, C, M, N, K);
    };

    gemm(x, W_kv_down, down_kv, S, DKV, DM);
    gemm(x, W_q_down, down_q, S, DQ, DM);
    gemm(x, W_k_rope, kr_raw, S, NH * DR, DM);
    gemm(down_kv, W_k_up, kc_raw, S, NH * DH, DKV);
    gemm(down_kv, W_v_up, v_raw, S, NH * DH, DKV);
    gemm(down_q, W_q_up, qc_raw, S, NH * DH, DQ);
    gemm(down_q, W_q_rope, qr_raw, S, NH * DR, DQ);

    const int total = NH * S * DQK;
    const float scale = 1.0f / sqrtf((float)DQK);
    assemble_qk_bf16_kernel<<<(total + 255) / 256, 256, 0, stream>>>(qc_raw, qr_raw, cosT, sinT, q_bf, scale, total);
    assemble_qk_bf16_kernel<<<(total + 255) / 256, 256, 0, stream>>>(kc_raw, kr_raw, cosT, sinT, k_bf, 1.0f, total);
    v_transpose_bf16_kernel<<<dim3(S / 64, DH / 64, NH), 256, 0, stream>>>(v_raw, vt);

    attn_mfma_kernel<<<dim3(S / 16, NH), 64, 0, stream>>>(q_bf, k_bf, vt, attn_out);

    gemm(attn_out, W_out, out, S, DM, DM);
}

// Round 3
// 469.991 us; speedup vs baseline: 9.5160x; 2.5559x over previous
//
#include <hip/hip_runtime.h>
#include <hip/hip_bf16.h>
#include <math.h>

#define S 2048
#define DM 2048
#define NH 16
#define DH 128
#define DR 64
#define DKV 512
#define DQ 1024
#define DQK 192  // DH + DR

typedef __bf16 bf16x8 __attribute__((ext_vector_type(8)));
typedef float f32x4 __attribute__((ext_vector_type(4)));
typedef unsigned short u16;

__device__ inline unsigned int pack2_bf16(float a, float b) {
    __hip_bfloat16 ha = __float2bfloat16(a);
    __hip_bfloat16 hb = __float2bfloat16(b);
    unsigned short ua = *reinterpret_cast<unsigned short*>(&ha);
    unsigned short ub = *reinterpret_cast<unsigned short*>(&hb);
    return (unsigned int)ua | ((unsigned int)ub << 16);
}
__device__ inline u16 f2bf(float v) {
    __hip_bfloat16 hb = __float2bfloat16(v);
    return *reinterpret_cast<u16*>(&hb);
}
__device__ inline float bf2f(u16 b) {
    return __bfloat162float(*reinterpret_cast<const __hip_bfloat16*>(&b));
}
__device__ inline void gload_lds16(const void* g, void* l) {
    __builtin_amdgcn_global_load_lds(
        (const __attribute__((address_space(1))) void*)g,
        (__attribute__((address_space(3))) void*)l, 16, 0, 0);
}
__device__ inline void store_out(float* p, float v) { *p = v; }
__device__ inline void store_out(u16* p, float v) { *p = f2bf(v); }

// ---------------- RoPE cos/sin table ----------------
__global__ void rope_table_kernel(float* __restrict__ cosT, float* __restrict__ sinT) {
    int idx = blockIdx.x * blockDim.x + threadIdx.x;
    if (idx >= S * (DR / 2)) return;
    int pos = idx / (DR / 2);
    int j   = idx % (DR / 2);
    float inv = __expf(-((float)(2 * j) / (float)DR) * logf(10000.0f));
    float ang = (float)pos * inv;
    cosT[idx] = cosf(ang);
    sinT[idx] = sinf(ang);
}

// ---------------- f32 -> bf16 elementwise (x) ----------------
__global__ void convert_bf16_kernel(const float* __restrict__ in, u16* __restrict__ outp, int n4) {
    int idx = blockIdx.x * blockDim.x + threadIdx.x;
    if (idx >= n4) return;
    float4 v = *reinterpret_cast<const float4*>(&in[(size_t)idx * 4]);
    uint2 w;
    w.x = pack2_bf16(v.x, v.y);
    w.y = pack2_bf16(v.z, v.w);
    *reinterpret_cast<uint2*>(&outp[(size_t)idx * 4]) = w;
}

// ---------------- transpose-convert: W f32 [K][N] -> WT bf16 [N][K] ----------------
__global__ __launch_bounds__(256) void wt_convert_kernel(const float* __restrict__ W,
                                                         u16* __restrict__ WT, int K, int N) {
    __shared__ u16 tile[64][65];
    const int n0 = blockIdx.x * 64;
    const int k0 = blockIdx.y * 64;
    const int tx = threadIdx.x & 15;
    const int ty = threadIdx.x >> 4;
#pragma unroll
    for (int rep = 0; rep < 4; ++rep) {
        int kk = rep * 16 + ty;
        float4 v = *reinterpret_cast<const float4*>(&W[(size_t)(k0 + kk) * N + n0 + tx * 4]);
        tile[kk][tx * 4 + 0] = f2bf(v.x);
        tile[kk][tx * 4 + 1] = f2bf(v.y);
        tile[kk][tx * 4 + 2] = f2bf(v.z);
        tile[kk][tx * 4 + 3] = f2bf(v.w);
    }
    __syncthreads();
#pragma unroll
    for (int rep = 0; rep < 4; ++rep) {
        int nn = rep * 16 + ty;
        uint2 w;
        w.x = (unsigned int)tile[tx * 4 + 0][nn] | ((unsigned int)tile[tx * 4 + 1][nn] << 16);
        w.y = (unsigned int)tile[tx * 4 + 2][nn] | ((unsigned int)tile[tx * 4 + 3][nn] << 16);
        *reinterpret_cast<uint2*>(&WT[(size_t)(n0 + nn) * K + k0 + tx * 4]) = w;
    }
}

// ---------------- bf16 MFMA GEMM: C = A[M,K] @ BT[N,K]^T, segmented N output ----------------
// 128x128 tile, BK=32, 4 waves (2x2), each wave 64x64 via 4x4 16x16x32 MFMAs.
// LDS tiles [128][32] bf16, 16B-slot swizzle slot^=(row>>1)&3 applied at BOTH stage-src and read.
template <typename OutT>
__global__ __launch_bounds__(256) void gemm_bf16_kernel(
    const u16* __restrict__ A, const u16* __restrict__ BT,
    OutT* __restrict__ C0, OutT* __restrict__ C1, OutT* __restrict__ C2,
    int n1, int n2, int ld0, int ld1, int ld2, int K) {
    __shared__ u16 lds[2][8192];  // per buf: A-tile u16[0..4095], B-tile u16[4096..8191]
    const int tid  = threadIdx.x;
    const int wave = tid >> 6;
    const int lane = tid & 63;
    const int c16  = lane & 15;
    const int g    = lane >> 4;
    const int bm = blockIdx.y * 128;
    const int bn = blockIdx.x * 128;
    const int wm = (wave >> 1) * 64;
    const int wn = (wave & 1) * 64;

    const int rowa0 = wave * 16 + (lane >> 2);  // staging row (round 0)
    const int slot  = lane & 3;                 // staging 16B slot

    f32x4 acc[4][4];
#pragma unroll
    for (int i = 0; i < 4; ++i)
#pragma unroll
        for (int j = 0; j < 4; ++j) acc[i][j] = f32x4{0.f, 0.f, 0.f, 0.f};

    auto stage = [&](int buf, int k0) {
#pragma unroll
        for (int r = 0; r < 2; ++r) {
            int row = rowa0 + r * 64;
            const u16* src = A + (size_t)(bm + row) * K + k0 + ((slot ^ ((row >> 1) & 3)) << 3);
            gload_lds16(src, &lds[buf][r * 2048 + wave * 512]);
        }
#pragma unroll
        for (int r = 0; r < 2; ++r) {
            int row = rowa0 + r * 64;
            const u16* src = BT + (size_t)(bn + row) * K + k0 + ((slot ^ ((row >> 1) & 3)) << 3);
            gload_lds16(src, &lds[buf][4096 + r * 2048 + wave * 512]);
        }
    };

    const int NT = K / 32;
    stage(0, 0);
    __syncthreads();
    int cur = 0;
    for (int t = 0; t < NT; ++t) {
        if (t + 1 < NT) stage(cur ^ 1, (t + 1) * 32);
        bf16x8 af[4], bfr[4];
#pragma unroll
        for (int i = 0; i < 4; ++i) {
            int row = wm + i * 16 + c16;
            af[i] = *reinterpret_cast<const bf16x8*>(
                (const char*)&lds[cur][0] + row * 64 + ((g ^ ((row >> 1) & 3)) << 4));
        }
#pragma unroll
        for (int j = 0; j < 4; ++j) {
            int row = wn + j * 16 + c16;
            bfr[j] = *reinterpret_cast<const bf16x8*>(
                (const char*)&lds[cur][4096] + row * 64 + ((g ^ ((row >> 1) & 3)) << 4));
        }
#pragma unroll
        for (int i = 0; i < 4; ++i)
#pragma unroll
            for (int j = 0; j < 4; ++j)
                acc[i][j] = __builtin_amdgcn_mfma_f32_16x16x32_bf16(af[i], bfr[j], acc[i][j], 0, 0, 0);
        __syncthreads();
        cur ^= 1;
    }

    // epilogue: D row = wm+i*16+g*4+r, col = wn+j*16+c16
    OutT* Cp; int ss, ld;
    if (bn < n1)      { Cp = C0; ss = 0;  ld = ld0; }
    else if (bn < n2) { Cp = C1; ss = n1; ld = ld1; }
    else              { Cp = C2; ss = n2; ld = ld2; }
#pragma unroll
    for (int i = 0; i < 4; ++i)
#pragma unroll
        for (int j = 0; j < 4; ++j) {
            int mrow = bm + wm + i * 16 + g * 4;
            size_t base = (size_t)mrow * ld + (bn - ss) + wn + j * 16 + c16;
#pragma unroll
            for (int r = 0; r < 4; ++r) store_out(&Cp[base + (size_t)r * ld], acc[i][j][r]);
        }
}

// ---------------- assemble q/k -> bf16 (NH, S, 192), RoPE on last 64, optional scale ----------------
__global__ void assemble_qk_bf16_kernel(const u16* __restrict__ c_raw,  // (s, NH*DH) bf16
                                        const u16* __restrict__ r_raw,  // (s, NH*DR) bf16
                                        const float* __restrict__ cosT,
                                        const float* __restrict__ sinT,
                                        u16* __restrict__ outp,  // (NH, S, DQK)
                                        float scale, int total) {
    int idx = blockIdx.x * blockDim.x + threadIdx.x;
    if (idx >= total) return;
    int d    = idx % DQK;
    int rest = idx / DQK;
    int pos  = rest % S;
    int h    = rest / S;
    float val;
    if (d < DH) {
        val = bf2f(c_raw[(size_t)pos * (NH * DH) + h * DH + d]);
    } else {
        int r = d - DH;
        int j = r >> 1;
        float t1 = bf2f(r_raw[(size_t)pos * (NH * DR) + h * DR + 2 * j]);
        float t2 = bf2f(r_raw[(size_t)pos * (NH * DR) + h * DR + 2 * j + 1]);
        float c  = cosT[pos * (DR / 2) + j];
        float s  = sinT[pos * (DR / 2) + j];
        val = (r & 1) ? (t1 * s + t2 * c) : (t1 * c - t2 * s);
    }
    outp[idx] = f2bf(val * scale);
}

// ---------------- V transpose: (s, NH*DH) bf16 -> (NH, DH, S) bf16 ----------------
__global__ __launch_bounds__(256) void v_transpose_bf16_kernel(const u16* __restrict__ v_bf,
                                                               u16* __restrict__ vt) {
    __shared__ u16 tile[64][65];
    const int j0 = blockIdx.x * 64;
    const int d0 = blockIdx.y * 64;
    const int h  = blockIdx.z;
    const int tx = threadIdx.x & 15;
    const int ty = threadIdx.x >> 4;
#pragma unroll
    for (int rep = 0; rep < 4; ++rep) {
        int j = rep * 16 + ty;
        ushort4 v = *reinterpret_cast<const ushort4*>(
            &v_bf[(size_t)(j0 + j) * (NH * DH) + h * DH + d0 + tx * 4]);
        tile[j][tx * 4 + 0] = v.x;
        tile[j][tx * 4 + 1] = v.y;
        tile[j][tx * 4 + 2] = v.z;
        tile[j][tx * 4 + 3] = v.w;
    }
    __syncthreads();
#pragma unroll
    for (int rep = 0; rep < 4; ++rep) {
        int d = rep * 16 + ty;
        uint2 w;
        w.x = (unsigned int)tile[tx * 4 + 0][d] | ((unsigned int)tile[tx * 4 + 1][d] << 16);
        w.y = (unsigned int)tile[tx * 4 + 2][d] | ((unsigned int)tile[tx * 4 + 3][d] << 16);
        *reinterpret_cast<uint2*>(&vt[((size_t)h * DH + d0 + d) * S + j0 + tx * 4]) = w;
    }
}

// ---------------- MFMA flash attention (bf16 out) ----------------
__global__ __launch_bounds__(64) void attn_mfma_kernel(const u16* __restrict__ q,   // (NH,S,192) pre-scaled
                                                       const u16* __restrict__ k,   // (NH,S,192)
                                                       const u16* __restrict__ vt,  // (NH,DH,S)
                                                       u16* __restrict__ outp) {    // (S, NH*DH) bf16
    const int h    = blockIdx.y;
    const int q0   = ((int)gridDim.x - 1 - (int)blockIdx.x) * 16;
    const int lane = threadIdx.x;
    const int col  = lane & 15;
    const int g    = lane >> 4;

    __shared__ __align__(16) char p_lds[1024];
    const int swz = (col & 3) << 4;

    bf16x8 qf[6];
    const u16* qbase = q + ((size_t)h * S + q0 + col) * DQK + g * 8;
#pragma unroll
    for (int c = 0; c < 6; ++c) qf[c] = *reinterpret_cast<const bf16x8*>(qbase + c * 32);

    f32x4 acc[8];
#pragma unroll
    for (int c = 0; c < 8; ++c) acc[c] = f32x4{0.f, 0.f, 0.f, 0.f};
    float m_run = -1e30f, l_run = 0.f;

    const int kend = q0 + 16;
    for (int j0 = 0; j0 < kend; j0 += 32) {
        const bool do_t1 = (j0 + 16) < kend;
        f32x4 st[2];
        st[0] = f32x4{0.f, 0.f, 0.f, 0.f};
        st[1] = f32x4{0.f, 0.f, 0.f, 0.f};
        const u16* kbase = k + ((size_t)h * S + j0 + col) * DQK + g * 8;
#pragma unroll
        for (int c = 0; c < 6; ++c) {
            bf16x8 kf = *reinterpret_cast<const bf16x8*>(kbase + c * 32);
            st[0] = __builtin_amdgcn_mfma_f32_16x16x32_bf16(kf, qf[c], st[0], 0, 0, 0);
        }
        if (do_t1) {
            const u16* kbase1 = kbase + (size_t)16 * DQK;
#pragma unroll
            for (int c = 0; c < 6; ++c) {
                bf16x8 kf = *reinterpret_cast<const bf16x8*>(kbase1 + c * 32);
                st[1] = __builtin_amdgcn_mfma_f32_16x16x32_bf16(kf, qf[c], st[1], 0, 0, 0);
            }
        } else {
            st[1] = f32x4{-1e30f, -1e30f, -1e30f, -1e30f};
        }
#pragma unroll
        for (int t = 0; t < 2; ++t) {
            if (j0 + 16 * t + 15 > q0) {
#pragma unroll
                for (int r = 0; r < 4; ++r) {
                    int key = j0 + 16 * t + 4 * g + r;
                    st[t][r] = (key > q0 + col) ? -1e30f : st[t][r];
                }
            }
        }
        float tmax = fmaxf(fmaxf(fmaxf(st[0][0], st[0][1]), fmaxf(st[0][2], st[0][3])),
                           fmaxf(fmaxf(st[1][0], st[1][1]), fmaxf(st[1][2], st[1][3])));
        tmax = fmaxf(tmax, __shfl_xor(tmax, 16));
        tmax = fmaxf(tmax, __shfl_xor(tmax, 32));
        float m_new = fmaxf(m_run, tmax);
        float r_scale = __expf(m_run - m_new);
        float p[8];
        float psum = 0.f;
#pragma unroll
        for (int t = 0; t < 2; ++t)
#pragma unroll
            for (int r = 0; r < 4; ++r) {
                float pv = __expf(st[t][r] - m_new);
                p[t * 4 + r] = pv;
                psum += pv;
            }
        psum += __shfl_xor(psum, 16);
        psum += __shfl_xor(psum, 32);
        l_run = l_run * r_scale + psum;
        m_run = m_new;
#pragma unroll
        for (int c = 0; c < 8; ++c) {
            acc[c][0] *= r_scale; acc[c][1] *= r_scale;
            acc[c][2] *= r_scale; acc[c][3] *= r_scale;
        }
        __syncthreads();
#pragma unroll
        for (int t = 0; t < 2; ++t) {
            uint2 w;
            w.x = pack2_bf16(p[t * 4 + 0], p[t * 4 + 1]);
            w.y = pack2_bf16(p[t * 4 + 2], p[t * 4 + 3]);
            int jb = (t * 16 + 4 * g) * 2;
            *reinterpret_cast<uint2*>(&p_lds[col * 64 + (jb ^ swz)]) = w;
        }
        __syncthreads();
        bf16x8 pf = *reinterpret_cast<const bf16x8*>(&p_lds[col * 64 + ((g * 16) ^ swz)]);
        const u16* vb = vt + ((size_t)h * DH + col) * S + j0 + g * 8;
#pragma unroll
        for (int c = 0; c < 8; ++c) {
            bf16x8 vf = *reinterpret_cast<const bf16x8*>(vb + (size_t)c * 16 * S);
            acc[c] = __builtin_amdgcn_mfma_f32_16x16x32_bf16(vf, pf, acc[c], 0, 0, 0);
        }
    }

    float inv_l = 1.0f / l_run;
#pragma unroll
    for (int c = 0; c < 8; ++c)
#pragma unroll
        for (int r = 0; r < 4; ++r)
            outp[(size_t)(q0 + col) * (NH * DH) + h * DH + 16 * c + 4 * g + r] = f2bf(acc[c][r] * inv_l);
}

// ---------------- launch ----------------
extern "C" void kernel_launch(void* const* d_in, const int* in_sizes, int n_in,
                              void* d_out, int out_size, void* d_ws, size_t ws_size,
                              hipStream_t stream) {
    const float* x         = (const float*)d_in[0];
    const float* W_kv_down = (const float*)d_in[2];
    const float* W_k_up    = (const float*)d_in[3];
    const float* W_v_up    = (const float*)d_in[4];
    const float* W_q_down  = (const float*)d_in[5];
    const float* W_q_up    = (const float*)d_in[6];
    const float* W_q_rope  = (const float*)d_in[7];
    const float* W_k_rope  = (const float*)d_in[8];
    const float* W_out     = (const float*)d_in[9];
    float* out = (float*)d_out;

    float* w = (float*)d_ws;
    float* cosT = w;
    float* sinT = w + (size_t)S * (DR / 2);
    u16* b = (u16*)(w + 2 * (size_t)S * (DR / 2));
    size_t off = 0;
    u16* x_bf    = b + off; off += (size_t)S * DM;
    u16* WT1     = b + off; off += (size_t)2560 * DM;    // [W_kv_down^T 512][W_q_down^T 1024][W_k_rope^T 1024], K=2048
    u16* WT2     = b + off; off += (size_t)4096 * DKV;   // [W_k_up^T 2048][W_v_up^T 2048], K=512
    u16* WT3     = b + off; off += (size_t)3072 * DQ;    // [W_q_up^T 2048][W_q_rope^T 1024], K=1024
    u16* WT4     = b + off; off += (size_t)DM * DM;      // W_out^T, K=2048
    u16* down_kv = b + off; off += (size_t)S * DKV;
    u16* down_q  = b + off; off += (size_t)S * DQ;
    u16* kr_bf   = b + off; off += (size_t)S * NH * DR;
    u16* kc_bf   = b + off; off += (size_t)S * NH * DH;
    u16* v_bf    = b + off; off += (size_t)S * NH * DH;
    u16* qc_bf   = b + off; off += (size_t)S * NH * DH;
    u16* qr_bf   = b + off; off += (size_t)S * NH * DR;
    u16* q_asm   = b + off; off += (size_t)NH * S * DQK;
    u16* k_asm   = b + off; off += (size_t)NH * S * DQK;
    u16* vt      = b + off; off += (size_t)NH * DH * S;
    u16* attn_bf = b + off; off += (size_t)S * NH * DH;

    rope_table_kernel<<<(S * (DR / 2) + 255) / 256, 256, 0, stream>>>(cosT, sinT);

    convert_bf16_kernel<<<((S * DM / 4) + 255) / 256, 256, 0, stream>>>(x, x_bf, S * DM / 4);

    auto wt = [&](const float* W, u16* dst, int K, int N) {
        wt_convert_kernel<<<dim3(N / 64, K / 64), 256, 0, stream>>>(W, dst, K, N);
    };
    wt(W_kv_down, WT1, DM, DKV);
    wt(W_q_down,  WT1 + (size_t)512 * DM, DM, DQ);
    wt(W_k_rope,  WT1 + (size_t)1536 * DM, DM, NH * DR);
    wt(W_k_up,    WT2, DKV, NH * DH);
    wt(W_v_up,    WT2 + (size_t)2048 * DKV, DKV, NH * DH);
    wt(W_q_up,    WT3, DQ, NH * DH);
    wt(W_q_rope,  WT3 + (size_t)2048 * DQ, DQ, NH * DR);
    wt(W_out,     WT4, DM, DM);

    // G1: x @ [W_kv_down | W_q_down | W_k_rope], N=2560, K=2048
    gemm_bf16_kernel<u16><<<dim3(2560 / 128, S / 128), 256, 0, stream>>>(
        x_bf, WT1, down_kv, down_q, kr_bf, 512, 1536, 512, 1024, 1024, DM);
    // G2: down_kv @ [W_k_up | W_v_up], N=4096, K=512
    gemm_bf16_kernel<u16><<<dim3(4096 / 128, S / 128), 256, 0, stream>>>(
        down_kv, WT2, kc_bf, v_bf, v_bf, 2048, 4096, 2048, 2048, 1, DKV);
    // G3: down_q @ [W_q_up | W_q_rope], N=3072, K=1024
    gemm_bf16_kernel<u16><<<dim3(3072 / 128, S / 128), 256, 0, stream>>>(
        down_q, WT3, qc_bf, qr_bf, qr_bf, 2048, 3072, 2048, 1024, 1, DQ);

    const int total = NH * S * DQK;
    const float scale = 1.0f / sqrtf((float)DQK);
    assemble_qk_bf16_kernel<<<(total + 255) / 256, 256, 0, stream>>>(qc_bf, qr_bf, cosT, sinT, q_asm, scale, total);
    assemble_qk_bf16_kernel<<<(total + 255) / 256, 256, 0, stream>>>(kc_bf, kr_bf, cosT, sinT, k_asm, 1.0f, total);
    v_transpose_bf16_kernel<<<dim3(S / 64, DH / 64, NH), 256, 0, stream>>>(v_bf, vt);

    attn_mfma_kernel<<<dim3(S / 16, NH), 64, 0, stream>>>(q_asm, k_asm, vt, attn_bf);

    // G4: attn_out @ W_out, N=2048, K=2048 -> fp32 d_out
    gemm_bf16_kernel<float><<<dim3(DM / 128, S / 128), 256, 0, stream>>>(
        attn_bf, WT4, out, out, out, DM, DM, DM, DM, DM, DM);
}

// Round 4
// 266.355 us; speedup vs baseline: 16.7913x; 1.7645x over previous
//
#include <hip/hip_runtime.h>
#include <hip/hip_bf16.h>
#include <math.h>

#define S 2048
#define DM 2048
#define NH 16
#define DH 128
#define DR 64
#define DKV 512
#define DQ 1024
#define DQK 192  // DH + DR

typedef __bf16 bf16x8 __attribute__((ext_vector_type(8)));
typedef float f32x4 __attribute__((ext_vector_type(4)));
typedef unsigned short u16;

__device__ inline unsigned int pack2_bf16(float a, float b) {
    __hip_bfloat16 ha = __float2bfloat16(a);
    __hip_bfloat16 hb = __float2bfloat16(b);
    unsigned short ua = *reinterpret_cast<unsigned short*>(&ha);
    unsigned short ub = *reinterpret_cast<unsigned short*>(&hb);
    return (unsigned int)ua | ((unsigned int)ub << 16);
}
__device__ inline u16 f2bf(float v) {
    __hip_bfloat16 hb = __float2bfloat16(v);
    return *reinterpret_cast<u16*>(&hb);
}
__device__ inline float bf2f(u16 b) {
    return __bfloat162float(*reinterpret_cast<const __hip_bfloat16*>(&b));
}
__device__ inline void gload_lds16(const void* g, void* l) {
    __builtin_amdgcn_global_load_lds(
        (const __attribute__((address_space(1))) void*)g,
        (__attribute__((address_space(3))) void*)l, 16, 0, 0);
}
__device__ inline void store_out(float* p, float v) { *p = v; }
__device__ inline void store_out(u16* p, float v) { *p = f2bf(v); }

// ---------------- RoPE cos/sin table ----------------
__global__ void rope_table_kernel(float* __restrict__ cosT, float* __restrict__ sinT) {
    int idx = blockIdx.x * blockDim.x + threadIdx.x;
    if (idx >= S * (DR / 2)) return;
    int pos = idx / (DR / 2);
    int j   = idx % (DR / 2);
    float inv = __expf(-((float)(2 * j) / (float)DR) * logf(10000.0f));
    float ang = (float)pos * inv;
    cosT[idx] = cosf(ang);
    sinT[idx] = sinf(ang);
}

// ---------------- f32 -> bf16 elementwise (x) ----------------
__global__ void convert_bf16_kernel(const float* __restrict__ in, u16* __restrict__ outp, int n4) {
    int idx = blockIdx.x * blockDim.x + threadIdx.x;
    if (idx >= n4) return;
    float4 v = *reinterpret_cast<const float4*>(&in[(size_t)idx * 4]);
    uint2 w;
    w.x = pack2_bf16(v.x, v.y);
    w.y = pack2_bf16(v.z, v.w);
    *reinterpret_cast<uint2*>(&outp[(size_t)idx * 4]) = w;
}

// ---------------- transpose-convert: W f32 [K][N] -> WT bf16 [N][K] ----------------
__global__ __launch_bounds__(256) void wt_convert_kernel(const float* __restrict__ W,
                                                         u16* __restrict__ WT, int K, int N) {
    __shared__ u16 tile[64][65];
    const int n0 = blockIdx.x * 64;
    const int k0 = blockIdx.y * 64;
    const int tx = threadIdx.x & 15;
    const int ty = threadIdx.x >> 4;
#pragma unroll
    for (int rep = 0; rep < 4; ++rep) {
        int kk = rep * 16 + ty;
        float4 v = *reinterpret_cast<const float4*>(&W[(size_t)(k0 + kk) * N + n0 + tx * 4]);
        tile[kk][tx * 4 + 0] = f2bf(v.x);
        tile[kk][tx * 4 + 1] = f2bf(v.y);
        tile[kk][tx * 4 + 2] = f2bf(v.z);
        tile[kk][tx * 4 + 3] = f2bf(v.w);
    }
    __syncthreads();
#pragma unroll
    for (int rep = 0; rep < 4; ++rep) {
        int nn = rep * 16 + ty;
        uint2 w;
        w.x = (unsigned int)tile[tx * 4 + 0][nn] | ((unsigned int)tile[tx * 4 + 1][nn] << 16);
        w.y = (unsigned int)tile[tx * 4 + 2][nn] | ((unsigned int)tile[tx * 4 + 3][nn] << 16);
        *reinterpret_cast<uint2*>(&WT[(size_t)(n0 + nn) * K + k0 + tx * 4]) = w;
    }
}

// ---------------- bf16 MFMA GEMM (unchanged from R3) ----------------
template <typename OutT>
__global__ __launch_bounds__(256) void gemm_bf16_kernel(
    const u16* __restrict__ A, const u16* __restrict__ BT,
    OutT* __restrict__ C0, OutT* __restrict__ C1, OutT* __restrict__ C2,
    int n1, int n2, int ld0, int ld1, int ld2, int K) {
    __shared__ u16 lds[2][8192];
    const int tid  = threadIdx.x;
    const int wave = tid >> 6;
    const int lane = tid & 63;
    const int c16  = lane & 15;
    const int g    = lane >> 4;
    const int bm = blockIdx.y * 128;
    const int bn = blockIdx.x * 128;
    const int wm = (wave >> 1) * 64;
    const int wn = (wave & 1) * 64;

    const int rowa0 = wave * 16 + (lane >> 2);
    const int slot  = lane & 3;

    f32x4 acc[4][4];
#pragma unroll
    for (int i = 0; i < 4; ++i)
#pragma unroll
        for (int j = 0; j < 4; ++j) acc[i][j] = f32x4{0.f, 0.f, 0.f, 0.f};

    auto stage = [&](int buf, int k0) {
#pragma unroll
        for (int r = 0; r < 2; ++r) {
            int row = rowa0 + r * 64;
            const u16* src = A + (size_t)(bm + row) * K + k0 + ((slot ^ ((row >> 1) & 3)) << 3);
            gload_lds16(src, &lds[buf][r * 2048 + wave * 512]);
        }
#pragma unroll
        for (int r = 0; r < 2; ++r) {
            int row = rowa0 + r * 64;
            const u16* src = BT + (size_t)(bn + row) * K + k0 + ((slot ^ ((row >> 1) & 3)) << 3);
            gload_lds16(src, &lds[buf][4096 + r * 2048 + wave * 512]);
        }
    };

    const int NT = K / 32;
    stage(0, 0);
    __syncthreads();
    int cur = 0;
    for (int t = 0; t < NT; ++t) {
        if (t + 1 < NT) stage(cur ^ 1, (t + 1) * 32);
        bf16x8 af[4], bfr[4];
#pragma unroll
        for (int i = 0; i < 4; ++i) {
            int row = wm + i * 16 + c16;
            af[i] = *reinterpret_cast<const bf16x8*>(
                (const char*)&lds[cur][0] + row * 64 + ((g ^ ((row >> 1) & 3)) << 4));
        }
#pragma unroll
        for (int j = 0; j < 4; ++j) {
            int row = wn + j * 16 + c16;
            bfr[j] = *reinterpret_cast<const bf16x8*>(
                (const char*)&lds[cur][4096] + row * 64 + ((g ^ ((row >> 1) & 3)) << 4));
        }
#pragma unroll
        for (int i = 0; i < 4; ++i)
#pragma unroll
            for (int j = 0; j < 4; ++j)
                acc[i][j] = __builtin_amdgcn_mfma_f32_16x16x32_bf16(af[i], bfr[j], acc[i][j], 0, 0, 0);
        __syncthreads();
        cur ^= 1;
    }

    OutT* Cp; int ss, ld;
    if (bn < n1)      { Cp = C0; ss = 0;  ld = ld0; }
    else if (bn < n2) { Cp = C1; ss = n1; ld = ld1; }
    else              { Cp = C2; ss = n2; ld = ld2; }
#pragma unroll
    for (int i = 0; i < 4; ++i)
#pragma unroll
        for (int j = 0; j < 4; ++j) {
            int mrow = bm + wm + i * 16 + g * 4;
            size_t base = (size_t)mrow * ld + (bn - ss) + wn + j * 16 + c16;
#pragma unroll
            for (int r = 0; r < 4; ++r) store_out(&Cp[base + (size_t)r * ld], acc[i][j][r]);
        }
}

// ---------------- assemble q/k -> bf16 (NH, S, 192), RoPE on last 64, optional scale ----------------
__global__ void assemble_qk_bf16_kernel(const u16* __restrict__ c_raw,
                                        const u16* __restrict__ r_raw,
                                        const float* __restrict__ cosT,
                                        const float* __restrict__ sinT,
                                        u16* __restrict__ outp,
                                        float scale, int total) {
    int idx = blockIdx.x * blockDim.x + threadIdx.x;
    if (idx >= total) return;
    int d    = idx % DQK;
    int rest = idx / DQK;
    int pos  = rest % S;
    int h    = rest / S;
    float val;
    if (d < DH) {
        val = bf2f(c_raw[(size_t)pos * (NH * DH) + h * DH + d]);
    } else {
        int r = d - DH;
        int j = r >> 1;
        float t1 = bf2f(r_raw[(size_t)pos * (NH * DR) + h * DR + 2 * j]);
        float t2 = bf2f(r_raw[(size_t)pos * (NH * DR) + h * DR + 2 * j + 1]);
        float c  = cosT[pos * (DR / 2) + j];
        float s  = sinT[pos * (DR / 2) + j];
        val = (r & 1) ? (t1 * s + t2 * c) : (t1 * c - t2 * s);
    }
    outp[idx] = f2bf(val * scale);
}

// ---------------- V transpose: (s, NH*DH) bf16 -> (NH, DH, S) bf16 ----------------
__global__ __launch_bounds__(256) void v_transpose_bf16_kernel(const u16* __restrict__ v_bf,
                                                               u16* __restrict__ vt) {
    __shared__ u16 tile[64][65];
    const int j0 = blockIdx.x * 64;
    const int d0 = blockIdx.y * 64;
    const int h  = blockIdx.z;
    const int tx = threadIdx.x & 15;
    const int ty = threadIdx.x >> 4;
#pragma unroll
    for (int rep = 0; rep < 4; ++rep) {
        int j = rep * 16 + ty;
        ushort4 v = *reinterpret_cast<const ushort4*>(
            &v_bf[(size_t)(j0 + j) * (NH * DH) + h * DH + d0 + tx * 4]);
        tile[j][tx * 4 + 0] = v.x;
        tile[j][tx * 4 + 1] = v.y;
        tile[j][tx * 4 + 2] = v.z;
        tile[j][tx * 4 + 3] = v.w;
    }
    __syncthreads();
#pragma unroll
    for (int rep = 0; rep < 4; ++rep) {
        int d = rep * 16 + ty;
        uint2 w;
        w.x = (unsigned int)tile[tx * 4 + 0][d] | ((unsigned int)tile[tx * 4 + 1][d] << 16);
        w.y = (unsigned int)tile[tx * 4 + 2][d] | ((unsigned int)tile[tx * 4 + 3][d] << 16);
        *reinterpret_cast<uint2*>(&vt[((size_t)h * DH + d0 + d) * S + j0 + tx * 4]) = w;
    }
}

// ---------------- MFMA flash attention v2 ----------------
// 4 waves/block, QBLK=64 (wave w owns rows q0+16w..+15), KV tiles of 32 staged in LDS
// (double-buffered, global_load_lds). Head-pair pinned per XCD for L2 residency.
__global__ __launch_bounds__(256) void attn_mfma_kernel(const u16* __restrict__ q,   // (NH,S,192) pre-scaled
                                                        const u16* __restrict__ k,   // (NH,S,192)
                                                        const u16* __restrict__ vt,  // (NH,DH,S)
                                                        u16* __restrict__ outp) {    // (S, NH*DH) bf16
    const int wgid = blockIdx.x;
    const int xcd  = wgid & 7;
    const int i    = wgid >> 3;  // 0..63 per xcd
    // balance: even head big-first, odd head small-first -> per-CU work ~const
    const int h  = (i < 32) ? (xcd * 2) : (xcd * 2 + 1);
    const int qt = (i < 32) ? (31 - i) : (i - 32);
    const int q0 = qt * 64;

    const int tid  = threadIdx.x;
    const int wave = tid >> 6;
    const int lane = tid & 63;
    const int col  = lane & 15;
    const int g    = lane >> 4;
    const int qw   = q0 + wave * 16;  // this wave's first q-row

    __shared__ u16 Kt[2][32 * DQK];   // [key][192], 16B slot-swizzled: slot^=(row&7)
    __shared__ u16 Vt[2][DH * 32];    // [d][32 keys], linear
    __shared__ __align__(16) char p_lds[4][1024];

    const int swz = (col & 3) << 4;

    // Q fragments: lane holds Q[qw+col][g*8+e + 32c]
    bf16x8 qf[6];
    const u16* qbase = q + ((size_t)h * S + qw + col) * DQK + g * 8;
#pragma unroll
    for (int c = 0; c < 6; ++c) qf[c] = *reinterpret_cast<const bf16x8*>(qbase + c * 32);

    f32x4 acc[8];
#pragma unroll
    for (int c = 0; c < 8; ++c) acc[c] = f32x4{0.f, 0.f, 0.f, 0.f};
    float m_run = -1e30f, l_run = 0.f;

    auto stage = [&](int buf, int j0) {
        // K: 768 16B-chunks; chunk ci -> (row=ci/24, slot=ci%24), src slot^=(row&7)
#pragma unroll
        for (int r = 0; r < 3; ++r) {
            int ci   = r * 256 + tid;
            int row  = ci / 24;
            int slot = ci % 24;
            int s2   = slot ^ (row & 7);
            const u16* src = k + ((size_t)h * S + j0 + row) * DQK + s2 * 8;
            gload_lds16(src, &Kt[buf][(r * 256 + wave * 64) * 8]);
        }
        // V: 512 16B-chunks; chunk ci -> (d=ci/4, key-chunk=ci%4), linear
#pragma unroll
        for (int r = 0; r < 2; ++r) {
            int ci = r * 256 + tid;
            int d  = ci >> 2;
            int ko = (ci & 3) * 8;
            const u16* src = vt + ((size_t)h * DH + d) * S + j0 + ko;
            gload_lds16(src, &Vt[buf][(r * 256 + wave * 64) * 8]);
        }
    };

    const int kend = q0 + 64;  // block-wide tile range
    stage(0, 0);
    __syncthreads();
    int cur = 0;
    for (int j0 = 0; j0 < kend; j0 += 32) {
        if (j0 + 32 < kend) stage(cur ^ 1, j0 + 32);
        // ---- QK^T from Kt[cur]
        f32x4 st[2];
        st[0] = f32x4{0.f, 0.f, 0.f, 0.f};
        st[1] = f32x4{0.f, 0.f, 0.f, 0.f};
#pragma unroll
        for (int t = 0; t < 2; ++t) {
            int row = 16 * t + col;
            const u16* kr = &Kt[cur][row * DQK];
            int sw = col & 7;
#pragma unroll
            for (int c = 0; c < 6; ++c) {
                bf16x8 kf = *reinterpret_cast<const bf16x8*>(kr + (((g + 4 * c) ^ sw) * 8));
                st[t] = __builtin_amdgcn_mfma_f32_16x16x32_bf16(kf, qf[c], st[t], 0, 0, 0);
            }
        }
        // ---- causal mask for this wave's rows (q = qw+col)
#pragma unroll
        for (int t = 0; t < 2; ++t) {
            if (j0 + 16 * t + 15 > qw) {
#pragma unroll
                for (int r = 0; r < 4; ++r) {
                    int key = j0 + 16 * t + 4 * g + r;
                    st[t][r] = (key > qw + col) ? -1e30f : st[t][r];
                }
            }
        }
        // ---- online softmax (per-lane stats)
        float tmax = fmaxf(fmaxf(fmaxf(st[0][0], st[0][1]), fmaxf(st[0][2], st[0][3])),
                           fmaxf(fmaxf(st[1][0], st[1][1]), fmaxf(st[1][2], st[1][3])));
        tmax = fmaxf(tmax, __shfl_xor(tmax, 16));
        tmax = fmaxf(tmax, __shfl_xor(tmax, 32));
        float m_new = fmaxf(m_run, tmax);
        float r_scale = __expf(m_run - m_new);
        float p[8];
        float psum = 0.f;
#pragma unroll
        for (int t = 0; t < 2; ++t)
#pragma unroll
            for (int r = 0; r < 4; ++r) {
                float pv = __expf(st[t][r] - m_new);
                p[t * 4 + r] = pv;
                psum += pv;
            }
        psum += __shfl_xor(psum, 16);
        psum += __shfl_xor(psum, 32);
        l_run = l_run * r_scale + psum;
        m_run = m_new;
#pragma unroll
        for (int c = 0; c < 8; ++c) {
            acc[c][0] *= r_scale; acc[c][1] *= r_scale;
            acc[c][2] *= r_scale; acc[c][3] *= r_scale;
        }
        // ---- P -> p_lds (per-wave region)
#pragma unroll
        for (int t = 0; t < 2; ++t) {
            uint2 w;
            w.x = pack2_bf16(p[t * 4 + 0], p[t * 4 + 1]);
            w.y = pack2_bf16(p[t * 4 + 2], p[t * 4 + 3]);
            int jb = (t * 16 + 4 * g) * 2;
            *reinterpret_cast<uint2*>(&p_lds[wave][col * 64 + (jb ^ swz)]) = w;
        }
        __syncthreads();  // P visible (and keeps waves in lockstep)
        // ---- PV from Vt[cur]
        bf16x8 pf = *reinterpret_cast<const bf16x8*>(&p_lds[wave][col * 64 + ((g * 16) ^ swz)]);
#pragma unroll
        for (int c = 0; c < 8; ++c) {
            bf16x8 vf = *reinterpret_cast<const bf16x8*>(&Vt[cur][(16 * c + col) * 32 + g * 8]);
            acc[c] = __builtin_amdgcn_mfma_f32_16x16x32_bf16(vf, pf, acc[c], 0, 0, 0);
        }
        __syncthreads();  // staged loads drained (vmcnt0) + all reads of cur done
        cur ^= 1;
    }

    float inv_l = 1.0f / l_run;
#pragma unroll
    for (int c = 0; c < 8; ++c)
#pragma unroll
        for (int r = 0; r < 4; ++r)
            outp[(size_t)(qw + col) * (NH * DH) + h * DH + 16 * c + 4 * g + r] = f2bf(acc[c][r] * inv_l);
}

// ---------------- launch ----------------
extern "C" void kernel_launch(void* const* d_in, const int* in_sizes, int n_in,
                              void* d_out, int out_size, void* d_ws, size_t ws_size,
                              hipStream_t stream) {
    const float* x         = (const float*)d_in[0];
    const float* W_kv_down = (const float*)d_in[2];
    const float* W_k_up    = (const float*)d_in[3];
    const float* W_v_up    = (const float*)d_in[4];
    const float* W_q_down  = (const float*)d_in[5];
    const float* W_q_up    = (const float*)d_in[6];
    const float* W_q_rope  = (const float*)d_in[7];
    const float* W_k_rope  = (const float*)d_in[8];
    const float* W_out     = (const float*)d_in[9];
    float* out = (float*)d_out;

    float* w = (float*)d_ws;
    float* cosT = w;
    float* sinT = w + (size_t)S * (DR / 2);
    u16* b = (u16*)(w + 2 * (size_t)S * (DR / 2));
    size_t off = 0;
    u16* x_bf    = b + off; off += (size_t)S * DM;
    u16* WT1     = b + off; off += (size_t)2560 * DM;
    u16* WT2     = b + off; off += (size_t)4096 * DKV;
    u16* WT3     = b + off; off += (size_t)3072 * DQ;
    u16* WT4     = b + off; off += (size_t)DM * DM;
    u16* down_kv = b + off; off += (size_t)S * DKV;
    u16* down_q  = b + off; off += (size_t)S * DQ;
    u16* kr_bf   = b + off; off += (size_t)S * NH * DR;
    u16* kc_bf   = b + off; off += (size_t)S * NH * DH;
    u16* v_bf    = b + off; off += (size_t)S * NH * DH;
    u16* qc_bf   = b + off; off += (size_t)S * NH * DH;
    u16* qr_bf   = b + off; off += (size_t)S * NH * DR;
    u16* q_asm   = b + off; off += (size_t)NH * S * DQK;
    u16* k_asm   = b + off; off += (size_t)NH * S * DQK;
    u16* vt      = b + off; off += (size_t)NH * DH * S;
    u16* attn_bf = b + off; off += (size_t)S * NH * DH;

    rope_table_kernel<<<(S * (DR / 2) + 255) / 256, 256, 0, stream>>>(cosT, sinT);

    convert_bf16_kernel<<<((S * DM / 4) + 255) / 256, 256, 0, stream>>>(x, x_bf, S * DM / 4);

    auto wt = [&](const float* W, u16* dst, int K, int N) {
        wt_convert_kernel<<<dim3(N / 64, K / 64), 256, 0, stream>>>(W, dst, K, N);
    };
    wt(W_kv_down, WT1, DM, DKV);
    wt(W_q_down,  WT1 + (size_t)512 * DM, DM, DQ);
    wt(W_k_rope,  WT1 + (size_t)1536 * DM, DM, NH * DR);
    wt(W_k_up,    WT2, DKV, NH * DH);
    wt(W_v_up,    WT2 + (size_t)2048 * DKV, DKV, NH * DH);
    wt(W_q_up,    WT3, DQ, NH * DH);
    wt(W_q_rope,  WT3 + (size_t)2048 * DQ, DQ, NH * DR);
    wt(W_out,     WT4, DM, DM);

    gemm_bf16_kernel<u16><<<dim3(2560 / 128, S / 128), 256, 0, stream>>>(
        x_bf, WT1, down_kv, down_q, kr_bf, 512, 1536, 512, 1024, 1024, DM);
    gemm_bf16_kernel<u16><<<dim3(4096 / 128, S / 128), 256, 0, stream>>>(
        down_kv, WT2, kc_bf, v_bf, v_bf, 2048, 4096, 2048, 2048, 1, DKV);
    gemm_bf16_kernel<u16><<<dim3(3072 / 128, S / 128), 256, 0, stream>>>(
        down_q, WT3, qc_bf, qr_bf, qr_bf, 2048, 3072, 2048, 1024, 1, DQ);

    const int total = NH * S * DQK;
    const float scale = 1.0f / sqrtf((float)DQK);
    assemble_qk_bf16_kernel<<<(total + 255) / 256, 256, 0, stream>>>(qc_bf, qr_bf, cosT, sinT, q_asm, scale, total);
    assemble_qk_bf16_kernel<<<(total + 255) / 256, 256, 0, stream>>>(kc_bf, kr_bf, cosT, sinT, k_asm, 1.0f, total);
    v_transpose_bf16_kernel<<<dim3(S / 64, DH / 64, NH), 256, 0, stream>>>(v_bf, vt);

    attn_mfma_kernel<<<512, 256, 0, stream>>>(q_asm, k_asm, vt, attn_bf);

    gemm_bf16_kernel<float><<<dim3(DM / 128, S / 128), 256, 0, stream>>>(
        attn_bf, WT4, out, out, out, DM, DM, DM, DM, DM, DM);
}

// Round 5
// 265.164 us; speedup vs baseline: 16.8666x; 1.0045x over previous
//
#include <hip/hip_runtime.h>
#include <hip/hip_bf16.h>
#include <math.h>

#define S 2048
#define DM 2048
#define NH 16
#define DH 128
#define DR 64
#define DKV 512
#define DQ 1024
#define DQK 192  // DH + DR

typedef __bf16 bf16x8 __attribute__((ext_vector_type(8)));
typedef float f32x4 __attribute__((ext_vector_type(4)));
typedef unsigned short u16;

__device__ inline unsigned int pack2_bf16(float a, float b) {
    __hip_bfloat16 ha = __float2bfloat16(a);
    __hip_bfloat16 hb = __float2bfloat16(b);
    unsigned short ua = *reinterpret_cast<unsigned short*>(&ha);
    unsigned short ub = *reinterpret_cast<unsigned short*>(&hb);
    return (unsigned int)ua | ((unsigned int)ub << 16);
}
__device__ inline u16 f2bf(float v) {
    __hip_bfloat16 hb = __float2bfloat16(v);
    return *reinterpret_cast<u16*>(&hb);
}
__device__ inline float bf2f(u16 b) {
    return __bfloat162float(*reinterpret_cast<const __hip_bfloat16*>(&b));
}
__device__ inline void gload_lds16(const void* g, void* l) {
    __builtin_amdgcn_global_load_lds(
        (const __attribute__((address_space(1))) void*)g,
        (__attribute__((address_space(3))) void*)l, 16, 0, 0);
}
__device__ inline void store_out(float* p, float v) { *p = v; }
__device__ inline void store_out(u16* p, float v) { *p = f2bf(v); }

// ---------------- RoPE cos/sin table ----------------
__global__ void rope_table_kernel(float* __restrict__ cosT, float* __restrict__ sinT) {
    int idx = blockIdx.x * blockDim.x + threadIdx.x;
    if (idx >= S * (DR / 2)) return;
    int pos = idx / (DR / 2);
    int j   = idx % (DR / 2);
    float inv = __expf(-((float)(2 * j) / (float)DR) * logf(10000.0f));
    float ang = (float)pos * inv;
    cosT[idx] = cosf(ang);
    sinT[idx] = sinf(ang);
}

// ---------------- f32 -> bf16 elementwise (x) ----------------
__global__ void convert_bf16_kernel(const float* __restrict__ in, u16* __restrict__ outp, int n4) {
    int idx = blockIdx.x * blockDim.x + threadIdx.x;
    if (idx >= n4) return;
    float4 v = *reinterpret_cast<const float4*>(&in[(size_t)idx * 4]);
    uint2 w;
    w.x = pack2_bf16(v.x, v.y);
    w.y = pack2_bf16(v.z, v.w);
    *reinterpret_cast<uint2*>(&outp[(size_t)idx * 4]) = w;
}

// ---------------- transpose-convert: W f32 [K][N] -> WT bf16 [N][K] ----------------
__global__ __launch_bounds__(256) void wt_convert_kernel(const float* __restrict__ W,
                                                         u16* __restrict__ WT, int K, int N) {
    __shared__ u16 tile[64][65];
    const int n0 = blockIdx.x * 64;
    const int k0 = blockIdx.y * 64;
    const int tx = threadIdx.x & 15;
    const int ty = threadIdx.x >> 4;
#pragma unroll
    for (int rep = 0; rep < 4; ++rep) {
        int kk = rep * 16 + ty;
        float4 v = *reinterpret_cast<const float4*>(&W[(size_t)(k0 + kk) * N + n0 + tx * 4]);
        tile[kk][tx * 4 + 0] = f2bf(v.x);
        tile[kk][tx * 4 + 1] = f2bf(v.y);
        tile[kk][tx * 4 + 2] = f2bf(v.z);
        tile[kk][tx * 4 + 3] = f2bf(v.w);
    }
    __syncthreads();
#pragma unroll
    for (int rep = 0; rep < 4; ++rep) {
        int nn = rep * 16 + ty;
        uint2 w;
        w.x = (unsigned int)tile[tx * 4 + 0][nn] | ((unsigned int)tile[tx * 4 + 1][nn] << 16);
        w.y = (unsigned int)tile[tx * 4 + 2][nn] | ((unsigned int)tile[tx * 4 + 3][nn] << 16);
        *reinterpret_cast<uint2*>(&WT[(size_t)(n0 + nn) * K + k0 + tx * 4]) = w;
    }
}

// ---------------- bf16 MFMA GEMM: C = A[M,K] @ BT[N,K]^T ----------------
// 64x128 tile, BK=32, 4 waves (2Mx2N), wave = 32x64 via 2x4 16x16x32 MFMAs.
// Paired-row LDS layout: 16B chunk (row,kc) at L=(row>>1)*8+(row&1)*4+kc -> conflict-free b128 reads.
template <typename OutT>
__global__ __launch_bounds__(256) void gemm_bf16_kernel(
    const u16* __restrict__ A, const u16* __restrict__ BT,
    OutT* __restrict__ C0, OutT* __restrict__ C1, OutT* __restrict__ C2,
    int n1, int n2, int ld0, int ld1, int ld2, int K) {
    __shared__ u16 lds[2][6144];  // A: u16 [0,2048); B: [2048,6144)
    const int tid  = threadIdx.x;
    const int wave = tid >> 6;
    const int lane = tid & 63;
    const int c16  = lane & 15;
    const int g    = lane >> 4;
    const int bm = blockIdx.y * 64;
    const int bn = blockIdx.x * 128;
    const int wm = (wave >> 1) * 32;
    const int wn = (wave & 1) * 64;

    f32x4 acc[2][4];
#pragma unroll
    for (int i = 0; i < 2; ++i)
#pragma unroll
        for (int j = 0; j < 4; ++j) acc[i][j] = f32x4{0.f, 0.f, 0.f, 0.f};

    auto stage = [&](int buf, int k0) {
        {   // A: 256 chunks, 1/thread
            int ci  = tid;
            int row = ((ci >> 3) << 1) + ((ci & 7) >> 2);
            int kc  = ci & 3;
            gload_lds16(A + (size_t)(bm + row) * K + k0 + kc * 8, &lds[buf][wave * 512]);
        }
#pragma unroll
        for (int r = 0; r < 2; ++r) {  // B: 512 chunks, 2/thread
            int ci  = r * 256 + tid;
            int row = ((ci >> 3) << 1) + ((ci & 7) >> 2);
            int kc  = ci & 3;
            gload_lds16(BT + (size_t)(bn + row) * K + k0 + kc * 8,
                        &lds[buf][2048 + (r * 256 + wave * 64) * 8]);
        }
    };

    const int NT = K / 32;
    stage(0, 0);
    __syncthreads();
    int cur = 0;
    for (int t = 0; t < NT; ++t) {
        if (t + 1 < NT) stage(cur ^ 1, (t + 1) * 32);
        bf16x8 af[2], bfr[4];
#pragma unroll
        for (int i = 0; i < 2; ++i) {
            int row = wm + i * 16 + c16;
            af[i] = *reinterpret_cast<const bf16x8*>(
                &lds[cur][(((row >> 1) << 3) + ((row & 1) << 2) + g) * 8]);
        }
#pragma unroll
        for (int j = 0; j < 4; ++j) {
            int row = wn + j * 16 + c16;
            bfr[j] = *reinterpret_cast<const bf16x8*>(
                &lds[cur][2048 + (((row >> 1) << 3) + ((row & 1) << 2) + g) * 8]);
        }
#pragma unroll
        for (int i = 0; i < 2; ++i)
#pragma unroll
            for (int j = 0; j < 4; ++j)
                acc[i][j] = __builtin_amdgcn_mfma_f32_16x16x32_bf16(af[i], bfr[j], acc[i][j], 0, 0, 0);
        __syncthreads();
        cur ^= 1;
    }

    OutT* Cp; int ss, ld;
    if (bn < n1)      { Cp = C0; ss = 0;  ld = ld0; }
    else if (bn < n2) { Cp = C1; ss = n1; ld = ld1; }
    else              { Cp = C2; ss = n2; ld = ld2; }
#pragma unroll
    for (int i = 0; i < 2; ++i)
#pragma unroll
        for (int j = 0; j < 4; ++j) {
            int mrow = bm + wm + i * 16 + g * 4;
            size_t base = (size_t)mrow * ld + (bn - ss) + wn + j * 16 + c16;
#pragma unroll
            for (int r = 0; r < 4; ++r) store_out(&Cp[base + (size_t)r * ld], acc[i][j][r]);
        }
}

// ---------------- assemble q/k -> bf16 (NH, S, 192), RoPE on last 64, optional scale ----------------
__global__ void assemble_qk_bf16_kernel(const u16* __restrict__ c_raw,
                                        const u16* __restrict__ r_raw,
                                        const float* __restrict__ cosT,
                                        const float* __restrict__ sinT,
                                        u16* __restrict__ outp,
                                        float scale, int total) {
    int idx = blockIdx.x * blockDim.x + threadIdx.x;
    if (idx >= total) return;
    int d    = idx % DQK;
    int rest = idx / DQK;
    int pos  = rest % S;
    int h    = rest / S;
    float val;
    if (d < DH) {
        val = bf2f(c_raw[(size_t)pos * (NH * DH) + h * DH + d]);
    } else {
        int r = d - DH;
        int j = r >> 1;
        float t1 = bf2f(r_raw[(size_t)pos * (NH * DR) + h * DR + 2 * j]);
        float t2 = bf2f(r_raw[(size_t)pos * (NH * DR) + h * DR + 2 * j + 1]);
        float c  = cosT[pos * (DR / 2) + j];
        float s  = sinT[pos * (DR / 2) + j];
        val = (r & 1) ? (t1 * s + t2 * c) : (t1 * c - t2 * s);
    }
    outp[idx] = f2bf(val * scale);
}

// ---------------- V transpose: (s, NH*DH) bf16 -> (NH, DH, S) bf16 ----------------
__global__ __launch_bounds__(256) void v_transpose_bf16_kernel(const u16* __restrict__ v_bf,
                                                               u16* __restrict__ vt) {
    __shared__ u16 tile[64][65];
    const int j0 = blockIdx.x * 64;
    const int d0 = blockIdx.y * 64;
    const int h  = blockIdx.z;
    const int tx = threadIdx.x & 15;
    const int ty = threadIdx.x >> 4;
#pragma unroll
    for (int rep = 0; rep < 4; ++rep) {
        int j = rep * 16 + ty;
        ushort4 v = *reinterpret_cast<const ushort4*>(
            &v_bf[(size_t)(j0 + j) * (NH * DH) + h * DH + d0 + tx * 4]);
        tile[j][tx * 4 + 0] = v.x;
        tile[j][tx * 4 + 1] = v.y;
        tile[j][tx * 4 + 2] = v.z;
        tile[j][tx * 4 + 3] = v.w;
    }
    __syncthreads();
#pragma unroll
    for (int rep = 0; rep < 4; ++rep) {
        int d = rep * 16 + ty;
        uint2 w;
        w.x = (unsigned int)tile[tx * 4 + 0][d] | ((unsigned int)tile[tx * 4 + 1][d] << 16);
        w.y = (unsigned int)tile[tx * 4 + 2][d] | ((unsigned int)tile[tx * 4 + 3][d] << 16);
        *reinterpret_cast<uint2*>(&vt[((size_t)h * DH + d0 + d) * S + j0 + tx * 4]) = w;
    }
}

// ---------------- MFMA flash attention v3 ----------------
// 4 waves/block, QBLK=64, KV tiles of 32 double-buffered via global_load_lds.
// Paired-row conflict-free LDS layouts; 1 barrier/tile; defer-max (THR=8).
__global__ __launch_bounds__(256) void attn_mfma_kernel(const u16* __restrict__ q,   // (NH,S,192) pre-scaled
                                                        const u16* __restrict__ k,   // (NH,S,192)
                                                        const u16* __restrict__ vt,  // (NH,DH,S)
                                                        u16* __restrict__ outp) {    // (S, NH*DH) bf16
    const int wgid = blockIdx.x;
    const int xcd  = wgid & 7;
    const int i    = wgid >> 3;  // 0..63 per xcd
    const int h  = (i < 32) ? (xcd * 2) : (xcd * 2 + 1);
    const int qt = (i < 32) ? (31 - i) : (i - 32);
    const int q0 = qt * 64;

    const int tid  = threadIdx.x;
    const int wave = tid >> 6;
    const int lane = tid & 63;
    const int col  = lane & 15;
    const int g    = lane >> 4;
    const int qw   = q0 + wave * 16;

    __shared__ u16 Kt[2][32 * DQK];        // paired-row layout, 12KB each
    __shared__ u16 Vt[2][DH * 32];         // paired-row layout, 8KB each
    __shared__ __align__(16) u16 p_lds[4][512];  // per-wave P, paired-row + kc-rotate

    // per-lane read base (16B-slot units): same formula for Kt/Vt/p_lds
    const int lslot = ((col >> 1) << 3) + ((col & 1) << 2);  // row-pair base
    const int xr    = (col >> 1) & 3;                        // P slot rotation

    // Q fragments: lane holds Q[qw+col][g*8+e + 32c]
    bf16x8 qf[6];
    const u16* qbase = q + ((size_t)h * S + qw + col) * DQK + g * 8;
#pragma unroll
    for (int c = 0; c < 6; ++c) qf[c] = *reinterpret_cast<const bf16x8*>(qbase + c * 32);

    f32x4 acc[8];
#pragma unroll
    for (int c = 0; c < 8; ++c) acc[c] = f32x4{0.f, 0.f, 0.f, 0.f};
    float m_run = -1e30f, l_run = 0.f;

    auto stage = [&](int buf, int j0) {
        // K: 768 chunks; L -> (c=L>>7, t=(L>>6)&1, rp=(L>>3)&7, sl=L&7)
#pragma unroll
        for (int r = 0; r < 3; ++r) {
            int ci  = r * 256 + tid;
            int row = ((ci >> 6) & 1) * 16 + (((ci >> 3) & 7) << 1) + ((ci & 7) >> 2);
            int s   = (ci >> 7) * 4 + (ci & 3);
            gload_lds16(k + ((size_t)h * S + j0 + row) * DQK + s * 8,
                        &Kt[buf][(r * 256 + wave * 64) * 8]);
        }
        // V: 512 chunks; L -> (c=L>>6, rp=(L>>3)&7, sl=L&7)
#pragma unroll
        for (int r = 0; r < 2; ++r) {
            int ci = r * 256 + tid;
            int d  = (ci >> 6) * 16 + (((ci >> 3) & 7) << 1) + ((ci & 7) >> 2);
            int kc = ci & 3;
            gload_lds16(vt + ((size_t)h * DH + d) * S + j0 + kc * 8,
                        &Vt[buf][(r * 256 + wave * 64) * 8]);
        }
    };

    const int kend = q0 + 64;
    stage(0, 0);
    __syncthreads();
    int cur = 0;
    for (int j0 = 0; j0 < kend; j0 += 32) {
        if (j0 + 32 < kend) stage(cur ^ 1, j0 + 32);
        // ---- QK^T from Kt[cur]
        f32x4 st[2];
        st[0] = f32x4{0.f, 0.f, 0.f, 0.f};
        st[1] = f32x4{0.f, 0.f, 0.f, 0.f};
#pragma unroll
        for (int t = 0; t < 2; ++t) {
#pragma unroll
            for (int c = 0; c < 6; ++c) {
                bf16x8 kf = *reinterpret_cast<const bf16x8*>(
                    &Kt[cur][(c * 128 + t * 64 + lslot + g) * 8]);
                st[t] = __builtin_amdgcn_mfma_f32_16x16x32_bf16(kf, qf[c], st[t], 0, 0, 0);
            }
        }
        // ---- causal mask (q = qw+col, key = j0+16t+4g+r)
#pragma unroll
        for (int t = 0; t < 2; ++t) {
            if (j0 + 16 * t + 15 > qw) {
#pragma unroll
                for (int r = 0; r < 4; ++r) {
                    int key = j0 + 16 * t + 4 * g + r;
                    st[t][r] = (key > qw + col) ? -1e30f : st[t][r];
                }
            }
        }
        // ---- online softmax with defer-max
        float tmax = fmaxf(fmaxf(fmaxf(st[0][0], st[0][1]), fmaxf(st[0][2], st[0][3])),
                           fmaxf(fmaxf(st[1][0], st[1][1]), fmaxf(st[1][2], st[1][3])));
        tmax = fmaxf(tmax, __shfl_xor(tmax, 16));
        tmax = fmaxf(tmax, __shfl_xor(tmax, 32));
        float m_new;
        if (__all(tmax - m_run <= 8.0f)) {
            m_new = m_run;  // defer: P bounded by e^8, no rescale
        } else {
            m_new = fmaxf(m_run, tmax);
            float r_scale = __expf(m_run - m_new);
            l_run *= r_scale;
#pragma unroll
            for (int c = 0; c < 8; ++c) {
                acc[c][0] *= r_scale; acc[c][1] *= r_scale;
                acc[c][2] *= r_scale; acc[c][3] *= r_scale;
            }
            m_run = m_new;
        }
        float p[8];
        float psum = 0.f;
#pragma unroll
        for (int t = 0; t < 2; ++t)
#pragma unroll
            for (int r = 0; r < 4; ++r) {
                float pv = __expf(st[t][r] - m_new);
                p[t * 4 + r] = pv;
                psum += pv;
            }
        psum += __shfl_xor(psum, 16);
        psum += __shfl_xor(psum, 32);
        l_run += psum;
        // ---- P -> p_lds (wave-private; lgkmcnt ordering by compiler, no barrier)
#pragma unroll
        for (int t = 0; t < 2; ++t) {
            uint2 w;
            w.x = pack2_bf16(p[t * 4 + 0], p[t * 4 + 1]);
            w.y = pack2_bf16(p[t * 4 + 2], p[t * 4 + 3]);
            int slot16 = lslot + ((2 * t + (g >> 1)) ^ xr);
            *reinterpret_cast<uint2*>(&p_lds[wave][slot16 * 8 + (g & 1) * 4]) = w;
        }
        bf16x8 pf = *reinterpret_cast<const bf16x8*>(&p_lds[wave][(lslot + (g ^ xr)) * 8]);
        // ---- PV from Vt[cur]
#pragma unroll
        for (int c = 0; c < 8; ++c) {
            bf16x8 vf = *reinterpret_cast<const bf16x8*>(&Vt[cur][(c * 64 + lslot + g) * 8]);
            acc[c] = __builtin_amdgcn_mfma_f32_16x16x32_bf16(vf, pf, acc[c], 0, 0, 0);
        }
        __syncthreads();  // all reads of cur done + staged cur^1 drained
        cur ^= 1;
    }

    float inv_l = 1.0f / l_run;
#pragma unroll
    for (int c = 0; c < 8; ++c)
#pragma unroll
        for (int r = 0; r < 4; ++r)
            outp[(size_t)(qw + col) * (NH * DH) + h * DH + 16 * c + 4 * g + r] = f2bf(acc[c][r] * inv_l);
}

// ---------------- launch ----------------
extern "C" void kernel_launch(void* const* d_in, const int* in_sizes, int n_in,
                              void* d_out, int out_size, void* d_ws, size_t ws_size,
                              hipStream_t stream) {
    const float* x         = (const float*)d_in[0];
    const float* W_kv_down = (const float*)d_in[2];
    const float* W_k_up    = (const float*)d_in[3];
    const float* W_v_up    = (const float*)d_in[4];
    const float* W_q_down  = (const float*)d_in[5];
    const float* W_q_up    = (const float*)d_in[6];
    const float* W_q_rope  = (const float*)d_in[7];
    const float* W_k_rope  = (const float*)d_in[8];
    const float* W_out     = (const float*)d_in[9];
    float* out = (float*)d_out;

    float* w = (float*)d_ws;
    float* cosT = w;
    float* sinT = w + (size_t)S * (DR / 2);
    u16* b = (u16*)(w + 2 * (size_t)S * (DR / 2));
    size_t off = 0;
    u16* x_bf    = b + off; off += (size_t)S * DM;
    u16* WT1     = b + off; off += (size_t)2560 * DM;
    u16* WT2     = b + off; off += (size_t)4096 * DKV;
    u16* WT3     = b + off; off += (size_t)3072 * DQ;
    u16* WT4     = b + off; off += (size_t)DM * DM;
    u16* down_kv = b + off; off += (size_t)S * DKV;
    u16* down_q  = b + off; off += (size_t)S * DQ;
    u16* kr_bf   = b + off; off += (size_t)S * NH * DR;
    u16* kc_bf   = b + off; off += (size_t)S * NH * DH;
    u16* v_bf    = b + off; off += (size_t)S * NH * DH;
    u16* qc_bf   = b + off; off += (size_t)S * NH * DH;
    u16* qr_bf   = b + off; off += (size_t)S * NH * DR;
    u16* q_asm   = b + off; off += (size_t)NH * S * DQK;
    u16* k_asm   = b + off; off += (size_t)NH * S * DQK;
    u16* vt      = b + off; off += (size_t)NH * DH * S;
    u16* attn_bf = b + off; off += (size_t)S * NH * DH;

    rope_table_kernel<<<(S * (DR / 2) + 255) / 256, 256, 0, stream>>>(cosT, sinT);

    convert_bf16_kernel<<<((S * DM / 4) + 255) / 256, 256, 0, stream>>>(x, x_bf, S * DM / 4);

    auto wt = [&](const float* W, u16* dst, int K, int N) {
        wt_convert_kernel<<<dim3(N / 64, K / 64), 256, 0, stream>>>(W, dst, K, N);
    };
    wt(W_kv_down, WT1, DM, DKV);
    wt(W_q_down,  WT1 + (size_t)512 * DM, DM, DQ);
    wt(W_k_rope,  WT1 + (size_t)1536 * DM, DM, NH * DR);
    wt(W_k_up,    WT2, DKV, NH * DH);
    wt(W_v_up,    WT2 + (size_t)2048 * DKV, DKV, NH * DH);
    wt(W_q_up,    WT3, DQ, NH * DH);
    wt(W_q_rope,  WT3 + (size_t)2048 * DQ, DQ, NH * DR);
    wt(W_out,     WT4, DM, DM);

    // G1: x @ [W_kv_down | W_q_down | W_k_rope], N=2560, K=2048
    gemm_bf16_kernel<u16><<<dim3(2560 / 128, S / 64), 256, 0, stream>>>(
        x_bf, WT1, down_kv, down_q, kr_bf, 512, 1536, 512, 1024, 1024, DM);
    // G2: down_kv @ [W_k_up | W_v_up], N=4096, K=512
    gemm_bf16_kernel<u16><<<dim3(4096 / 128, S / 64), 256, 0, stream>>>(
        down_kv, WT2, kc_bf, v_bf, v_bf, 2048, 4096, 2048, 2048, 1, DKV);
    // G3: down_q @ [W_q_up | W_q_rope], N=3072, K=1024
    gemm_bf16_kernel<u16><<<dim3(3072 / 128, S / 64), 256, 0, stream>>>(
        down_q, WT3, qc_bf, qr_bf, qr_bf, 2048, 3072, 2048, 1024, 1, DQ);

    const int total = NH * S * DQK;
    const float scale = 1.0f / sqrtf((float)DQK);
    assemble_qk_bf16_kernel<<<(total + 255) / 256, 256, 0, stream>>>(qc_bf, qr_bf, cosT, sinT, q_asm, scale, total);
    assemble_qk_bf16_kernel<<<(total + 255) / 256, 256, 0, stream>>>(kc_bf, kr_bf, cosT, sinT, k_asm, 1.0f, total);
    v_transpose_bf16_kernel<<<dim3(S / 64, DH / 64, NH), 256, 0, stream>>>(v_bf, vt);

    attn_mfma_kernel<<<512, 256, 0, stream>>>(q_asm, k_asm, vt, attn_bf);

    // G4: attn_out @ W_out, N=2048, K=2048 -> fp32 d_out
    gemm_bf16_kernel<float><<<dim3(DM / 128, S / 64), 256, 0, stream>>>(
        attn_bf, WT4, out, out, out, DM, DM, DM, DM, DM, DM);
}

// Round 6
// 262.022 us; speedup vs baseline: 17.0689x; 1.0120x over previous
//
#include <hip/hip_runtime.h>
#include <hip/hip_bf16.h>
#include <math.h>

#define S 2048
#define DM 2048
#define NH 16
#define DH 128
#define DR 64
#define DKV 512
#define DQ 1024
#define DQK 192  // DH + DR

typedef __bf16 bf16x8 __attribute__((ext_vector_type(8)));
typedef float f32x4 __attribute__((ext_vector_type(4)));
typedef unsigned short u16;

__device__ inline unsigned int pack2_bf16(float a, float b) {
    __hip_bfloat16 ha = __float2bfloat16(a);
    __hip_bfloat16 hb = __float2bfloat16(b);
    unsigned short ua = *reinterpret_cast<unsigned short*>(&ha);
    unsigned short ub = *reinterpret_cast<unsigned short*>(&hb);
    return (unsigned int)ua | ((unsigned int)ub << 16);
}
__device__ inline u16 f2bf(float v) {
    __hip_bfloat16 hb = __float2bfloat16(v);
    return *reinterpret_cast<u16*>(&hb);
}
__device__ inline float bf2f(u16 b) {
    return __bfloat162float(*reinterpret_cast<const __hip_bfloat16*>(&b));
}
__device__ inline void gload_lds16(const void* g, void* l) {
    __builtin_amdgcn_global_load_lds(
        (const __attribute__((address_space(1))) void*)g,
        (__attribute__((address_space(3))) void*)l, 16, 0, 0);
}
__device__ inline void store_out(float* p, float v) { *p = v; }
__device__ inline void store_out(u16* p, float v) { *p = f2bf(v); }

// ---------------- RoPE cos/sin table ----------------
__global__ void rope_table_kernel(float* __restrict__ cosT, float* __restrict__ sinT) {
    int idx = blockIdx.x * blockDim.x + threadIdx.x;
    if (idx >= S * (DR / 2)) return;
    int pos = idx / (DR / 2);
    int j   = idx % (DR / 2);
    float inv = __expf(-((float)(2 * j) / (float)DR) * logf(10000.0f));
    float ang = (float)pos * inv;
    cosT[idx] = cosf(ang);
    sinT[idx] = sinf(ang);
}

// ---------------- f32 -> bf16 elementwise (x) ----------------
__global__ void convert_bf16_kernel(const float* __restrict__ in, u16* __restrict__ outp, int n4) {
    int idx = blockIdx.x * blockDim.x + threadIdx.x;
    if (idx >= n4) return;
    float4 v = *reinterpret_cast<const float4*>(&in[(size_t)idx * 4]);
    uint2 w;
    w.x = pack2_bf16(v.x, v.y);
    w.y = pack2_bf16(v.z, v.w);
    *reinterpret_cast<uint2*>(&outp[(size_t)idx * 4]) = w;
}

// ---------------- transpose-convert: W f32 [K][N] -> WT bf16 [N][K] ----------------
__global__ __launch_bounds__(256) void wt_convert_kernel(const float* __restrict__ W,
                                                         u16* __restrict__ WT, int K, int N) {
    __shared__ u16 tile[64][65];
    const int n0 = blockIdx.x * 64;
    const int k0 = blockIdx.y * 64;
    const int tx = threadIdx.x & 15;
    const int ty = threadIdx.x >> 4;
#pragma unroll
    for (int rep = 0; rep < 4; ++rep) {
        int kk = rep * 16 + ty;
        float4 v = *reinterpret_cast<const float4*>(&W[(size_t)(k0 + kk) * N + n0 + tx * 4]);
        tile[kk][tx * 4 + 0] = f2bf(v.x);
        tile[kk][tx * 4 + 1] = f2bf(v.y);
        tile[kk][tx * 4 + 2] = f2bf(v.z);
        tile[kk][tx * 4 + 3] = f2bf(v.w);
    }
    __syncthreads();
#pragma unroll
    for (int rep = 0; rep < 4; ++rep) {
        int nn = rep * 16 + ty;
        uint2 w;
        w.x = (unsigned int)tile[tx * 4 + 0][nn] | ((unsigned int)tile[tx * 4 + 1][nn] << 16);
        w.y = (unsigned int)tile[tx * 4 + 2][nn] | ((unsigned int)tile[tx * 4 + 3][nn] << 16);
        *reinterpret_cast<uint2*>(&WT[(size_t)(n0 + nn) * K + k0 + tx * 4]) = w;
    }
}

// ---------------- bf16 MFMA GEMM: C = A[M,K] @ BT[N,K]^T ----------------
// 64x128 tile, BK=32, 4 waves (2Mx2N), wave = 32x64 via 2x4 16x16x32 MFMAs.
// Conflict-free LDS slot map (consecutive-8-lane phase model):
//   slot(row,kc) = (row>>1)*8 + ((4*(row&1)+kc) ^ ((row>>1)&7)); staging uses inverse on global src.
template <typename OutT>
__global__ __launch_bounds__(256) void gemm_bf16_kernel(
    const u16* __restrict__ A, const u16* __restrict__ BT,
    OutT* __restrict__ C0, OutT* __restrict__ C1, OutT* __restrict__ C2,
    int n1, int n2, int ld0, int ld1, int ld2, int K) {
    __shared__ u16 lds[2][6144];  // A slots [0,256); B slots [256,768) (u16*8 each)
    const int tid  = threadIdx.x;
    const int wave = tid >> 6;
    const int lane = tid & 63;
    const int c16  = lane & 15;
    const int g    = lane >> 4;
    const int bm = blockIdx.y * 64;
    const int bn = blockIdx.x * 128;
    const int wm = (wave >> 1) * 32;
    const int wn = (wave & 1) * 64;

    f32x4 acc[2][4];
#pragma unroll
    for (int i = 0; i < 2; ++i)
#pragma unroll
        for (int j = 0; j < 4; ++j) acc[i][j] = f32x4{0.f, 0.f, 0.f, 0.f};

    auto stage = [&](int buf, int k0) {
        {   // A: 256 chunks, 1/thread; inverse map L -> (row,kc)
            int L = tid;
            int rp = L >> 3, e = L & 7, x = e ^ (rp & 7);
            int row = 2 * rp + (x >> 2), kc = x & 3;
            gload_lds16(A + (size_t)(bm + row) * K + k0 + kc * 8, &lds[buf][wave * 512]);
        }
#pragma unroll
        for (int r = 0; r < 2; ++r) {  // B: 512 chunks, 2/thread
            int L = r * 256 + tid;
            int rp = L >> 3, e = L & 7, x = e ^ (rp & 7);
            int row = 2 * rp + (x >> 2), kc = x & 3;
            gload_lds16(BT + (size_t)(bn + row) * K + k0 + kc * 8,
                        &lds[buf][2048 + (r * 256 + wave * 64) * 8]);
        }
    };

    const int NT = K / 32;
    stage(0, 0);
    __syncthreads();
    int cur = 0;
    for (int t = 0; t < NT; ++t) {
        if (t + 1 < NT) stage(cur ^ 1, (t + 1) * 32);
        bf16x8 af[2], bfr[4];
#pragma unroll
        for (int i = 0; i < 2; ++i) {
            int row  = wm + i * 16 + c16;
            int slot = ((row >> 1) << 3) + ((((row & 1) << 2) + g) ^ ((row >> 1) & 7));
            af[i] = *reinterpret_cast<const bf16x8*>(&lds[cur][slot * 8]);
        }
#pragma unroll
        for (int j = 0; j < 4; ++j) {
            int row  = wn + j * 16 + c16;
            int slot = ((row >> 1) << 3) + ((((row & 1) << 2) + g) ^ ((row >> 1) & 7));
            bfr[j] = *reinterpret_cast<const bf16x8*>(&lds[cur][2048 + slot * 8]);
        }
#pragma unroll
        for (int i = 0; i < 2; ++i)
#pragma unroll
            for (int j = 0; j < 4; ++j)
                acc[i][j] = __builtin_amdgcn_mfma_f32_16x16x32_bf16(af[i], bfr[j], acc[i][j], 0, 0, 0);
        __syncthreads();
        cur ^= 1;
    }

    OutT* Cp; int ss, ld;
    if (bn < n1)      { Cp = C0; ss = 0;  ld = ld0; }
    else if (bn < n2) { Cp = C1; ss = n1; ld = ld1; }
    else              { Cp = C2; ss = n2; ld = ld2; }
#pragma unroll
    for (int i = 0; i < 2; ++i)
#pragma unroll
        for (int j = 0; j < 4; ++j) {
            int mrow = bm + wm + i * 16 + g * 4;
            size_t base = (size_t)mrow * ld + (bn - ss) + wn + j * 16 + c16;
#pragma unroll
            for (int r = 0; r < 4; ++r) store_out(&Cp[base + (size_t)r * ld], acc[i][j][r]);
        }
}

// ---------------- assemble q/k -> bf16 (NH, S, 192), RoPE on last 64, optional scale ----------------
__global__ void assemble_qk_bf16_kernel(const u16* __restrict__ c_raw,
                                        const u16* __restrict__ r_raw,
                                        const float* __restrict__ cosT,
                                        const float* __restrict__ sinT,
                                        u16* __restrict__ outp,
                                        float scale, int total) {
    int idx = blockIdx.x * blockDim.x + threadIdx.x;
    if (idx >= total) return;
    int d    = idx % DQK;
    int rest = idx / DQK;
    int pos  = rest % S;
    int h    = rest / S;
    float val;
    if (d < DH) {
        val = bf2f(c_raw[(size_t)pos * (NH * DH) + h * DH + d]);
    } else {
        int r = d - DH;
        int j = r >> 1;
        float t1 = bf2f(r_raw[(size_t)pos * (NH * DR) + h * DR + 2 * j]);
        float t2 = bf2f(r_raw[(size_t)pos * (NH * DR) + h * DR + 2 * j + 1]);
        float c  = cosT[pos * (DR / 2) + j];
        float s  = sinT[pos * (DR / 2) + j];
        val = (r & 1) ? (t1 * s + t2 * c) : (t1 * c - t2 * s);
    }
    outp[idx] = f2bf(val * scale);
}

// ---------------- V transpose: (s, NH*DH) bf16 -> (NH, DH, S) bf16 ----------------
__global__ __launch_bounds__(256) void v_transpose_bf16_kernel(const u16* __restrict__ v_bf,
                                                               u16* __restrict__ vt) {
    __shared__ u16 tile[64][65];
    const int j0 = blockIdx.x * 64;
    const int d0 = blockIdx.y * 64;
    const int h  = blockIdx.z;
    const int tx = threadIdx.x & 15;
    const int ty = threadIdx.x >> 4;
#pragma unroll
    for (int rep = 0; rep < 4; ++rep) {
        int j = rep * 16 + ty;
        ushort4 v = *reinterpret_cast<const ushort4*>(
            &v_bf[(size_t)(j0 + j) * (NH * DH) + h * DH + d0 + tx * 4]);
        tile[j][tx * 4 + 0] = v.x;
        tile[j][tx * 4 + 1] = v.y;
        tile[j][tx * 4 + 2] = v.z;
        tile[j][tx * 4 + 3] = v.w;
    }
    __syncthreads();
#pragma unroll
    for (int rep = 0; rep < 4; ++rep) {
        int d = rep * 16 + ty;
        uint2 w;
        w.x = (unsigned int)tile[tx * 4 + 0][d] | ((unsigned int)tile[tx * 4 + 1][d] << 16);
        w.y = (unsigned int)tile[tx * 4 + 2][d] | ((unsigned int)tile[tx * 4 + 3][d] << 16);
        *reinterpret_cast<uint2*>(&vt[((size_t)h * DH + d0 + d) * S + j0 + tx * 4]) = w;
    }
}

// ---------------- MFMA flash attention v4 ----------------
// 4 waves/block, QBLK=64, KV tiles of 32 double-buffered via global_load_lds.
// Conflict-free slot maps (consecutive-8-lane phase model), both-sides applied.
__global__ __launch_bounds__(256) void attn_mfma_kernel(const u16* __restrict__ q,   // (NH,S,192) pre-scaled
                                                        const u16* __restrict__ k,   // (NH,S,192)
                                                        const u16* __restrict__ vt,  // (NH,DH,S)
                                                        u16* __restrict__ outp) {    // (S, NH*DH) bf16
    const int wgid = blockIdx.x;
    const int xcd  = wgid & 7;
    const int i    = wgid >> 3;  // 0..63 per xcd
    const int h  = (i < 32) ? (xcd * 2) : (xcd * 2 + 1);
    const int qt = (i < 32) ? (31 - i) : (i - 32);
    const int q0 = qt * 64;

    const int tid  = threadIdx.x;
    const int wave = tid >> 6;
    const int lane = tid & 63;
    const int col  = lane & 15;
    const int g    = lane >> 4;
    const int qw   = q0 + wave * 16;

    __shared__ u16 Kt[2][32 * DQK];              // slot(row,ch)=row*24+8*(ch>>3)+((ch&7)^(row&7))
    __shared__ u16 Vt[2][DH * 32];               // slot(d,kc)=(d>>1)*8+((4*(d&1)+kc)^((d>>1)&7))
    __shared__ __align__(16) u16 p_lds[4][512];  // per-wave P, same slot form as Vt (row=q)

    const int r7  = col & 7;          // K row-class
    const int pv7 = (col >> 1) & 7;   // V/P row-pair class
    const int pvb = (col & 1) << 2;

    // Q fragments: lane holds Q[qw+col][g*8+e + 32c]
    bf16x8 qf[6];
    const u16* qbase = q + ((size_t)h * S + qw + col) * DQK + g * 8;
#pragma unroll
    for (int c = 0; c < 6; ++c) qf[c] = *reinterpret_cast<const bf16x8*>(qbase + c * 32);

    f32x4 acc[8];
#pragma unroll
    for (int c = 0; c < 8; ++c) acc[c] = f32x4{0.f, 0.f, 0.f, 0.f};
    float m_run = -1e30f, l_run = 0.f;

    auto stage = [&](int buf, int j0) {
        // K: 768 chunks; inverse: row=L/24, rem=L%24, ch=8*(rem>>3)+((rem&7)^(row&7))
#pragma unroll
        for (int r = 0; r < 3; ++r) {
            int L   = r * 256 + tid;
            int row = L / 24, rem = L - row * 24;
            int ch  = ((rem >> 3) << 3) + ((rem & 7) ^ (row & 7));
            gload_lds16(k + ((size_t)h * S + j0 + row) * DQK + ch * 8,
                        &Kt[buf][(r * 256 + wave * 64) * 8]);
        }
        // V: 512 chunks; inverse: rp=L>>3, x=(L&7)^(rp&7), d=2rp+(x>>2), kc=x&3
#pragma unroll
        for (int r = 0; r < 2; ++r) {
            int L  = r * 256 + tid;
            int rp = L >> 3, x = (L & 7) ^ (rp & 7);
            int d  = 2 * rp + (x >> 2), kc = x & 3;
            gload_lds16(vt + ((size_t)h * DH + d) * S + j0 + kc * 8,
                        &Vt[buf][(r * 256 + wave * 64) * 8]);
        }
    };

    const int kend = q0 + 64;
    stage(0, 0);
    __syncthreads();
    int cur = 0;
    for (int j0 = 0; j0 < kend; j0 += 32) {
        if (j0 + 32 < kend) stage(cur ^ 1, j0 + 32);
        // ---- QK^T from Kt[cur]
        f32x4 st[2];
        st[0] = f32x4{0.f, 0.f, 0.f, 0.f};
        st[1] = f32x4{0.f, 0.f, 0.f, 0.f};
#pragma unroll
        for (int t = 0; t < 2; ++t) {
            int rb = (16 * t + col) * 24;
#pragma unroll
            for (int c = 0; c < 6; ++c) {
                int ch   = g + 4 * c;
                int slot = rb + ((ch >> 3) << 3) + ((ch & 7) ^ r7);
                bf16x8 kf = *reinterpret_cast<const bf16x8*>(&Kt[cur][slot * 8]);
                st[t] = __builtin_amdgcn_mfma_f32_16x16x32_bf16(kf, qf[c], st[t], 0, 0, 0);
            }
        }
        // ---- causal mask (q = qw+col, key = j0+16t+4g+r)
#pragma unroll
        for (int t = 0; t < 2; ++t) {
            if (j0 + 16 * t + 15 > qw) {
#pragma unroll
                for (int r = 0; r < 4; ++r) {
                    int key = j0 + 16 * t + 4 * g + r;
                    st[t][r] = (key > qw + col) ? -1e30f : st[t][r];
                }
            }
        }
        // ---- online softmax with defer-max
        float tmax = fmaxf(fmaxf(fmaxf(st[0][0], st[0][1]), fmaxf(st[0][2], st[0][3])),
                           fmaxf(fmaxf(st[1][0], st[1][1]), fmaxf(st[1][2], st[1][3])));
        tmax = fmaxf(tmax, __shfl_xor(tmax, 16));
        tmax = fmaxf(tmax, __shfl_xor(tmax, 32));
        float m_new;
        if (__all(tmax - m_run <= 8.0f)) {
            m_new = m_run;  // defer: P bounded by e^8, no rescale
        } else {
            m_new = fmaxf(m_run, tmax);
            float r_scale = __expf(m_run - m_new);
            l_run *= r_scale;
#pragma unroll
            for (int c = 0; c < 8; ++c) {
                acc[c][0] *= r_scale; acc[c][1] *= r_scale;
                acc[c][2] *= r_scale; acc[c][3] *= r_scale;
            }
            m_run = m_new;
        }
        float p[8];
        float psum = 0.f;
#pragma unroll
        for (int t = 0; t < 2; ++t)
#pragma unroll
            for (int r = 0; r < 4; ++r) {
                float pv = __expf(st[t][r] - m_new);
                p[t * 4 + r] = pv;
                psum += pv;
            }
        psum += __shfl_xor(psum, 16);
        psum += __shfl_xor(psum, 32);
        l_run += psum;
        // ---- P -> p_lds (wave-private; chunk = 2t+(g>>1), half = g&1)
#pragma unroll
        for (int t = 0; t < 2; ++t) {
            uint2 w;
            w.x = pack2_bf16(p[t * 4 + 0], p[t * 4 + 1]);
            w.y = pack2_bf16(p[t * 4 + 2], p[t * 4 + 3]);
            int ch   = 2 * t + (g >> 1);
            int slot = ((col >> 1) << 3) + ((pvb + ch) ^ pv7);
            *reinterpret_cast<uint2*>(&p_lds[wave][slot * 8 + (g & 1) * 4]) = w;
        }
        {
            int slot = ((col >> 1) << 3) + ((pvb + g) ^ pv7);
            bf16x8 pf = *reinterpret_cast<const bf16x8*>(&p_lds[wave][slot * 8]);
            // ---- PV from Vt[cur]
#pragma unroll
            for (int c = 0; c < 8; ++c) {
                int d  = 16 * c + col;
                int vs = ((d >> 1) << 3) + ((pvb + g) ^ pv7);
                bf16x8 vf = *reinterpret_cast<const bf16x8*>(&Vt[cur][vs * 8]);
                acc[c] = __builtin_amdgcn_mfma_f32_16x16x32_bf16(vf, pf, acc[c], 0, 0, 0);
            }
        }
        __syncthreads();  // all reads of cur done + staged cur^1 drained
        cur ^= 1;
    }

    float inv_l = 1.0f / l_run;
#pragma unroll
    for (int c = 0; c < 8; ++c)
#pragma unroll
        for (int r = 0; r < 4; ++r)
            outp[(size_t)(qw + col) * (NH * DH) + h * DH + 16 * c + 4 * g + r] = f2bf(acc[c][r] * inv_l);
}

// ---------------- launch ----------------
extern "C" void kernel_launch(void* const* d_in, const int* in_sizes, int n_in,
                              void* d_out, int out_size, void* d_ws, size_t ws_size,
                              hipStream_t stream) {
    const float* x         = (const float*)d_in[0];
    const float* W_kv_down = (const float*)d_in[2];
    const float* W_k_up    = (const float*)d_in[3];
    const float* W_v_up    = (const float*)d_in[4];
    const float* W_q_down  = (const float*)d_in[5];
    const float* W_q_up    = (const float*)d_in[6];
    const float* W_q_rope  = (const float*)d_in[7];
    const float* W_k_rope  = (const float*)d_in[8];
    const float* W_out     = (const float*)d_in[9];
    float* out = (float*)d_out;

    float* w = (float*)d_ws;
    float* cosT = w;
    float* sinT = w + (size_t)S * (DR / 2);
    u16* b = (u16*)(w + 2 * (size_t)S * (DR / 2));
    size_t off = 0;
    u16* x_bf    = b + off; off += (size_t)S * DM;
    u16* WT1     = b + off; off += (size_t)2560 * DM;
    u16* WT2     = b + off; off += (size_t)4096 * DKV;
    u16* WT3     = b + off; off += (size_t)3072 * DQ;
    u16* WT4     = b + off; off += (size_t)DM * DM;
    u16* down_kv = b + off; off += (size_t)S * DKV;
    u16* down_q  = b + off; off += (size_t)S * DQ;
    u16* kr_bf   = b + off; off += (size_t)S * NH * DR;
    u16* kc_bf   = b + off; off += (size_t)S * NH * DH;
    u16* v_bf    = b + off; off += (size_t)S * NH * DH;
    u16* qc_bf   = b + off; off += (size_t)S * NH * DH;
    u16* qr_bf   = b + off; off += (size_t)S * NH * DR;
    u16* q_asm   = b + off; off += (size_t)NH * S * DQK;
    u16* k_asm   = b + off; off += (size_t)NH * S * DQK;
    u16* vt      = b + off; off += (size_t)NH * DH * S;
    u16* attn_bf = b + off; off += (size_t)S * NH * DH;

    rope_table_kernel<<<(S * (DR / 2) + 255) / 256, 256, 0, stream>>>(cosT, sinT);

    convert_bf16_kernel<<<((S * DM / 4) + 255) / 256, 256, 0, stream>>>(x, x_bf, S * DM / 4);

    auto wt = [&](const float* W, u16* dst, int K, int N) {
        wt_convert_kernel<<<dim3(N / 64, K / 64), 256, 0, stream>>>(W, dst, K, N);
    };
    wt(W_kv_down, WT1, DM, DKV);
    wt(W_q_down,  WT1 + (size_t)512 * DM, DM, DQ);
    wt(W_k_rope,  WT1 + (size_t)1536 * DM, DM, NH * DR);
    wt(W_k_up,    WT2, DKV, NH * DH);
    wt(W_v_up,    WT2 + (size_t)2048 * DKV, DKV, NH * DH);
    wt(W_q_up,    WT3, DQ, NH * DH);
    wt(W_q_rope,  WT3 + (size_t)2048 * DQ, DQ, NH * DR);
    wt(W_out,     WT4, DM, DM);

    // G1: x @ [W_kv_down | W_q_down | W_k_rope], N=2560, K=2048
    gemm_bf16_kernel<u16><<<dim3(2560 / 128, S / 64), 256, 0, stream>>>(
        x_bf, WT1, down_kv, down_q, kr_bf, 512, 1536, 512, 1024, 1024, DM);
    // G2: down_kv @ [W_k_up | W_v_up], N=4096, K=512
    gemm_bf16_kernel<u16><<<dim3(4096 / 128, S / 64), 256, 0, stream>>>(
        down_kv, WT2, kc_bf, v_bf, v_bf, 2048, 4096, 2048, 2048, 1, DKV);
    // G3: down_q @ [W_q_up | W_q_rope], N=3072, K=1024
    gemm_bf16_kernel<u16><<<dim3(3072 / 128, S / 64), 256, 0, stream>>>(
        down_q, WT3, qc_bf, qr_bf, qr_bf, 2048, 3072, 2048, 1024, 1, DQ);

    const int total = NH * S * DQK;
    const float scale = 1.0f / sqrtf((float)DQK);
    assemble_qk_bf16_kernel<<<(total + 255) / 256, 256, 0, stream>>>(qc_bf, qr_bf, cosT, sinT, q_asm, scale, total);
    assemble_qk_bf16_kernel<<<(total + 255) / 256, 256, 0, stream>>>(kc_bf, kr_bf, cosT, sinT, k_asm, 1.0f, total);
    v_transpose_bf16_kernel<<<dim3(S / 64, DH / 64, NH), 256, 0, stream>>>(v_bf, vt);

    attn_mfma_kernel<<<512, 256, 0, stream>>>(q_asm, k_asm, vt, attn_bf);

    // G4: attn_out @ W_out, N=2048, K=2048 -> fp32 d_out
    gemm_bf16_kernel<float><<<dim3(DM / 128, S / 64), 256, 0, stream>>>(
        attn_bf, WT4, out, out, out, DM, DM, DM, DM, DM, DM);
}